// Round 3
// baseline (353.705 us; speedup 1.0000x reference)
//
#include <hip/hip_runtime.h>
#include <stdint.h>

typedef __bf16 bf16x8 __attribute__((ext_vector_type(8)));
typedef float f32x4 __attribute__((ext_vector_type(4)));
typedef float f32x2 __attribute__((ext_vector_type(2)));
typedef unsigned short u16x4 __attribute__((ext_vector_type(4)));
typedef unsigned short u16x8 __attribute__((ext_vector_type(8)));

#define NTOK 20000
#define HIW  256
#define HD   2048

static __device__ __forceinline__ unsigned short f2bf(float f) {
  union { float f; unsigned u; } c; c.f = f;
  unsigned u = c.u + (0x7fffu + ((c.u >> 16) & 1u));   // RNE
  return (unsigned short)(u >> 16);
}
static __device__ __forceinline__ float bf2f(unsigned short h) {
  union { unsigned u; float f; } c; c.u = ((unsigned)h) << 16;
  return c.f;
}

#define WRED(x) { x += __shfl_xor(x,32); x += __shfl_xor(x,16); x += __shfl_xor(x,8); \
                  x += __shfl_xor(x,4);  x += __shfl_xor(x,2);  x += __shfl_xor(x,1); }

// scal: 0=lam 1=-lam 2=1-li 3=li 4=dc 5=alpha_c 6=css 7=cbar
__global__ __launch_bounds__(256) void k_lambda(
    const float* __restrict__ lq1, const float* __restrict__ lk1,
    const float* __restrict__ lq2, const float* __restrict__ lk2,
    const float* __restrict__ bq1, const float* __restrict__ bk1,
    const float* __restrict__ bq2, const float* __restrict__ bk2,
    const int* __restrict__ layer, float* __restrict__ scal) {
  int t = threadIdx.x;
  float p1 = lq1[t] * lk1[t], p2 = lq2[t] * lk2[t];
  float d1 = 0.f, d2 = 0.f;
  #pragma unroll
  for (int u = 0; u < 8; ++u) {
    d1 += bq1[t * 8 + u] * bk1[t * 8 + u];
    d2 += bq2[t * 8 + u] * bk2[t * 8 + u];
  }
  WRED(p1); WRED(p2); WRED(d1); WRED(d2);
  __shared__ float red[16];
  int w = t >> 6;
  if ((t & 63) == 0) { red[w] = p1; red[4 + w] = p2; red[8 + w] = d1; red[12 + w] = d2; }
  __syncthreads();
  if (t == 0) {
    float s1 = red[0] + red[1] + red[2] + red[3];
    float s2 = red[4] + red[5] + red[6] + red[7];
    float dd1 = red[8] + red[9] + red[10] + red[11];
    float dd2 = red[12] + red[13] + red[14] + red[15];
    float li = 0.8f - 0.6f * expf(-0.3f * (float)layer[0]);
    float lam = expf(s1) - expf(s2) + li;
    scal[0] = lam; scal[1] = -lam; scal[2] = 1.0f - li; scal[3] = li;
    scal[4] = dd1 - lam * dd2;
  }
}

// column sums of k and v -> partials [160][256]
__global__ __launch_bounds__(256) void k_colsum(
    const float* __restrict__ kk, const float* __restrict__ vv,
    float* __restrict__ skp, float* __restrict__ svp) {
  int b = blockIdx.x, t = threadIdx.x;
  float s1 = 0.f, s2 = 0.f;
  for (int r = 0; r < 125; ++r) {
    size_t n = (size_t)(b * 125 + r) * HIW + t;
    s1 += kk[n];
    s2 += vv[n];
  }
  skp[b * 256 + t] = s1;
  svp[b * 256 + t] = s2;
}

// S_part[z] += k^T v over n-chunk z (hi/lo split bf16 MFMA, fp32-quality)
__global__ __launch_bounds__(256) void k_s(
    const float* __restrict__ kk, const float* __restrict__ vv,
    float* __restrict__ S_part) {
  __shared__ unsigned short SH[4 * 128 * 72];
  unsigned short* Ahi = SH;
  unsigned short* Alo = SH + 128 * 72;
  unsigned short* Bhi = SH + 2 * 128 * 72;
  unsigned short* Blo = SH + 3 * 128 * 72;
  const int t = threadIdx.x, lane = t & 63, wave = t >> 6;
  const int i0 = blockIdx.x * 128, j0 = blockIdx.y * 128, z = blockIdx.z;
  const int wr = (wave >> 1) * 64, wc = (wave & 1) * 64;
  const int r15 = lane & 15, kg = (lane >> 4) * 8;
  f32x4 acc[4][4];
  #pragma unroll
  for (int m = 0; m < 4; ++m)
    #pragma unroll
    for (int n = 0; n < 4; ++n) acc[m][n] = (f32x4){0.f, 0.f, 0.f, 0.f};
  const int r0 = t >> 5, c4 = (t & 31) * 4;
  for (int kt = 0; kt < 10; ++kt) {
    __syncthreads();
    #pragma unroll
    for (int it = 0; it < 8; ++it) {
      int nl = it * 8 + r0;
      int nn = kt * 64 + nl;
      bool valid = nn < 625;
      int gn = z * 625 + nn;
      f32x4 a = {0.f, 0.f, 0.f, 0.f}, b = {0.f, 0.f, 0.f, 0.f};
      if (valid) {
        a = *(const f32x4*)&kk[(size_t)gn * HIW + i0 + c4];
        b = *(const f32x4*)&vv[(size_t)gn * HIW + j0 + c4];
      }
      #pragma unroll
      for (int u = 0; u < 4; ++u) {
        unsigned short h = f2bf(a[u]);
        Ahi[(c4 + u) * 72 + nl] = h;
        Alo[(c4 + u) * 72 + nl] = f2bf(a[u] - bf2f(h));
        h = f2bf(b[u]);
        Bhi[(c4 + u) * 72 + nl] = h;
        Blo[(c4 + u) * 72 + nl] = f2bf(b[u] - bf2f(h));
      }
    }
    __syncthreads();
    #pragma unroll
    for (int ks = 0; ks < 2; ++ks) {
      const int ko = ks * 32 + kg;
      bf16x8 ah[4], al[4], bh[4], bl[4];
      #pragma unroll
      for (int m = 0; m < 4; ++m) {
        ah[m] = *(const bf16x8*)&Ahi[(wr + m * 16 + r15) * 72 + ko];
        al[m] = *(const bf16x8*)&Alo[(wr + m * 16 + r15) * 72 + ko];
      }
      #pragma unroll
      for (int n = 0; n < 4; ++n) {
        bh[n] = *(const bf16x8*)&Bhi[(wc + n * 16 + r15) * 72 + ko];
        bl[n] = *(const bf16x8*)&Blo[(wc + n * 16 + r15) * 72 + ko];
      }
      #pragma unroll
      for (int m = 0; m < 4; ++m)
        #pragma unroll
        for (int n = 0; n < 4; ++n) {
          acc[m][n] = __builtin_amdgcn_mfma_f32_16x16x32_bf16(ah[m], bh[n], acc[m][n], 0, 0, 0);
          acc[m][n] = __builtin_amdgcn_mfma_f32_16x16x32_bf16(ah[m], bl[n], acc[m][n], 0, 0, 0);
          acc[m][n] = __builtin_amdgcn_mfma_f32_16x16x32_bf16(al[m], bh[n], acc[m][n], 0, 0, 0);
        }
    }
  }
  const int rg = (lane >> 4) * 4;
  #pragma unroll
  for (int m = 0; m < 4; ++m)
    #pragma unroll
    for (int n = 0; n < 4; ++n)
      #pragma unroll
      for (int r = 0; r < 4; ++r)
        S_part[(size_t)z * 65536 + (i0 + wr + m * 16 + rg + r) * 256 + (j0 + wc + n * 16 + r15)] =
            acc[m][n][r];
}

// Pc_part[z] = Wq1 Wk1^T - lam Wq2 Wk2^T (split-K over 2048, hi/lo MFMA)
__global__ __launch_bounds__(256) void k_pc(
    const float* __restrict__ Wq1, const float* __restrict__ Wk1,
    const float* __restrict__ Wq2, const float* __restrict__ Wk2,
    const float* __restrict__ scal, float* __restrict__ Pc_part) {
  __shared__ unsigned short SH[4 * 128 * 72];
  unsigned short* Ahi = SH;
  unsigned short* Alo = SH + 128 * 72;
  unsigned short* Bhi = SH + 2 * 128 * 72;
  unsigned short* Blo = SH + 3 * 128 * 72;
  const int t = threadIdx.x, lane = t & 63, wave = t >> 6;
  const int i0 = blockIdx.x * 128, j0 = blockIdx.y * 128, z = blockIdx.z;
  const int wr = (wave >> 1) * 64, wc = (wave & 1) * 64;
  const int r15 = lane & 15, kg = (lane >> 4) * 8;
  const float nlam = scal[1];
  f32x4 acc[4][4];
  #pragma unroll
  for (int m = 0; m < 4; ++m)
    #pragma unroll
    for (int n = 0; n < 4; ++n) acc[m][n] = (f32x4){0.f, 0.f, 0.f, 0.f};
  const int srow = t >> 1, sh = (t & 1) * 32;
  for (int pair = 0; pair < 2; ++pair) {
    const float* Wa = pair ? Wq2 : Wq1;
    const float* Wb = pair ? Wk2 : Wk1;
    const float asc = pair ? nlam : 1.0f;
    for (int kt = 0; kt < 8; ++kt) {
      const int kb = z * 512 + kt * 64 + sh;
      __syncthreads();
      #pragma unroll
      for (int c = 0; c < 8; ++c) {
        f32x4 a = *(const f32x4*)&Wa[(size_t)(i0 + srow) * HD + kb + c * 4];
        f32x4 b = *(const f32x4*)&Wb[(size_t)(j0 + srow) * HD + kb + c * 4];
        #pragma unroll
        for (int u = 0; u < 4; ++u) {
          float av = a[u] * asc;
          unsigned short h = f2bf(av);
          Ahi[srow * 72 + sh + c * 4 + u] = h;
          Alo[srow * 72 + sh + c * 4 + u] = f2bf(av - bf2f(h));
          h = f2bf(b[u]);
          Bhi[srow * 72 + sh + c * 4 + u] = h;
          Blo[srow * 72 + sh + c * 4 + u] = f2bf(b[u] - bf2f(h));
        }
      }
      __syncthreads();
      #pragma unroll
      for (int ks = 0; ks < 2; ++ks) {
        const int ko = ks * 32 + kg;
        bf16x8 ah[4], al[4], bh[4], bl[4];
        #pragma unroll
        for (int m = 0; m < 4; ++m) {
          ah[m] = *(const bf16x8*)&Ahi[(wr + m * 16 + r15) * 72 + ko];
          al[m] = *(const bf16x8*)&Alo[(wr + m * 16 + r15) * 72 + ko];
        }
        #pragma unroll
        for (int n = 0; n < 4; ++n) {
          bh[n] = *(const bf16x8*)&Bhi[(wc + n * 16 + r15) * 72 + ko];
          bl[n] = *(const bf16x8*)&Blo[(wc + n * 16 + r15) * 72 + ko];
        }
        #pragma unroll
        for (int m = 0; m < 4; ++m)
          #pragma unroll
          for (int n = 0; n < 4; ++n) {
            acc[m][n] = __builtin_amdgcn_mfma_f32_16x16x32_bf16(ah[m], bh[n], acc[m][n], 0, 0, 0);
            acc[m][n] = __builtin_amdgcn_mfma_f32_16x16x32_bf16(ah[m], bl[n], acc[m][n], 0, 0, 0);
            acc[m][n] = __builtin_amdgcn_mfma_f32_16x16x32_bf16(al[m], bh[n], acc[m][n], 0, 0, 0);
          }
      }
    }
  }
  const int rg = (lane >> 4) * 4;
  #pragma unroll
  for (int m = 0; m < 4; ++m)
    #pragma unroll
    for (int n = 0; n < 4; ++n)
      #pragma unroll
      for (int r = 0; r < 4; ++r)
        Pc_part[(size_t)z * 65536 + (i0 + wr + m * 16 + rg + r) * 256 + (j0 + wc + n * 16 + r15)] =
            acc[m][n][r];
}

__global__ __launch_bounds__(256) void k_sred(
    const float* __restrict__ S_part, const float* __restrict__ Pc_part,
    const float* __restrict__ skp, const float* __restrict__ svp,
    float* __restrict__ S, float* __restrict__ ST, float* __restrict__ Pc,
    float* __restrict__ sk, float* __restrict__ sv) {
  int b = blockIdx.x, t = threadIdx.x;
  if (b < 256) {
    int idx = b * 256 + t;
    float s = 0.f;
    for (int z = 0; z < 32; ++z) s += S_part[(size_t)z * 65536 + idx];
    S[idx] = s;
    ST[t * 256 + b] = s;
  } else if (b < 512) {
    int idx = (b - 256) * 256 + t;
    float s = 0.f;
    #pragma unroll
    for (int z = 0; z < 4; ++z) s += Pc_part[(size_t)z * 65536 + idx];
    Pc[idx] = s;
  } else {
    float s1 = 0.f, s2 = 0.f;
    for (int z = 0; z < 160; ++z) { s1 += skp[z * 256 + t]; s2 += svp[z * 256 + t]; }
    sk[t] = s1; sv[t] = s2;
  }
}

// gc = Wk1 bq1 - lam Wk2 bq2 ; uc = Wq1 bk1 - lam Wq2 bk2
__global__ __launch_bounds__(256) void k_mv(
    const float* __restrict__ Wk1, const float* __restrict__ Wk2,
    const float* __restrict__ Wq1, const float* __restrict__ Wq2,
    const float* __restrict__ bq1, const float* __restrict__ bq2,
    const float* __restrict__ bk1, const float* __restrict__ bk2,
    const float* __restrict__ scal, float* __restrict__ gc, float* __restrict__ uc) {
  int b = blockIdx.x, t = threadIdx.x, lane = t & 63, w = t >> 6;
  bool dogc = b < 16;
  const float* A1 = dogc ? Wk1 : Wq1;
  const float* A2 = dogc ? Wk2 : Wq2;
  const float* x1 = dogc ? bq1 : bk1;
  const float* x2 = dogc ? bq2 : bk2;
  float* outv = dogc ? gc : uc;
  float lam = scal[0];
  int rb = (b & 15) * 16 + w * 4;
  for (int q2 = 0; q2 < 4; ++q2) {
    int row = rb + q2;
    float s1 = 0.f, s2 = 0.f;
    #pragma unroll
    for (int c = 0; c < 8; ++c) {
      int kk2 = c * 256 + lane * 4;
      f32x4 a1 = *(const f32x4*)&A1[(size_t)row * HD + kk2];
      f32x4 a2 = *(const f32x4*)&A2[(size_t)row * HD + kk2];
      f32x4 v1 = *(const f32x4*)&x1[kk2];
      f32x4 v2 = *(const f32x4*)&x2[kk2];
      #pragma unroll
      for (int u = 0; u < 4; ++u) { s1 += a1[u] * v1[u]; s2 += a2[u] * v2[u]; }
    }
    WRED(s1); WRED(s2);
    if (lane == 0) outv[row] = s1 - lam * s2;
  }
}

// Ac = Pc @ S ; tc = Pc @ sk ; r = S^T gc ; alpha_c = gc . sk
__global__ __launch_bounds__(256) void k_ac(
    const float* __restrict__ Pc, const float* __restrict__ S,
    const float* __restrict__ gc, const float* __restrict__ sk,
    float* __restrict__ Ac, float* __restrict__ tc, float* __restrict__ rv,
    float* __restrict__ scal) {
  int b = blockIdx.x, t = threadIdx.x;
  if (b < 32) {
    __shared__ float Pt[32][68];
    __shared__ float St[64][68];
    int i0 = (b >> 2) * 32, j0 = (b & 3) * 64;
    int ti = t >> 5, tj = t & 31;
    float acc[4][2] = {};
    for (int kt = 0; kt < 256; kt += 64) {
      __syncthreads();
      {
        int rr = t >> 3, c8 = (t & 7) * 8;
        *(f32x4*)&Pt[rr][c8] = *(const f32x4*)&Pc[(i0 + rr) * 256 + kt + c8];
        *(f32x4*)&Pt[rr][c8 + 4] = *(const f32x4*)&Pc[(i0 + rr) * 256 + kt + c8 + 4];
      }
      {
        int rr = t >> 2, c16 = (t & 3) * 16;
        #pragma unroll
        for (int c = 0; c < 4; ++c)
          *(f32x4*)&St[rr][c16 + c * 4] = *(const f32x4*)&S[(kt + rr) * 256 + j0 + c16 + c * 4];
      }
      __syncthreads();
      #pragma unroll 8
      for (int k2 = 0; k2 < 64; ++k2) {
        float a[4];
        #pragma unroll
        for (int u = 0; u < 4; ++u) a[u] = Pt[ti * 4 + u][k2];
        f32x2 b2 = *(const f32x2*)&St[k2][tj * 2];
        #pragma unroll
        for (int u = 0; u < 4; ++u) { acc[u][0] += a[u] * b2[0]; acc[u][1] += a[u] * b2[1]; }
      }
    }
    #pragma unroll
    for (int u = 0; u < 4; ++u) {
      Ac[(i0 + ti * 4 + u) * 256 + j0 + tj * 2] = acc[u][0];
      Ac[(i0 + ti * 4 + u) * 256 + j0 + tj * 2 + 1] = acc[u][1];
    }
  } else if (b == 32) {
    int lane = t & 63, w = t >> 6;
    f32x4 sk4 = *(const f32x4*)&sk[lane * 4];
    for (int ii = 0; ii < 64; ++ii) {
      int i = w * 64 + ii;
      f32x4 p4 = *(const f32x4*)&Pc[i * 256 + lane * 4];
      float s = p4[0] * sk4[0] + p4[1] * sk4[1] + p4[2] * sk4[2] + p4[3] * sk4[3];
      WRED(s);
      if (lane == 0) tc[i] = s;
    }
  } else {
    float s = 0.f;
    #pragma unroll 4
    for (int i = 0; i < 256; ++i) s += gc[i] * S[i * 256 + t];
    rv[t] = s;
    if (t < 64) {
      f32x4 g4 = *(const f32x4*)&gc[t * 4];
      f32x4 sk4 = *(const f32x4*)&sk[t * 4];
      float a = g4[0] * sk4[0] + g4[1] * sk4[1] + g4[2] * sk4[2] + g4[3] * sk4[3];
      WRED(a);
      if (t == 0) scal[5] = a;
    }
  }
}

// w = Wv^T sv ; cc = Wv^T r + alpha_c*bv + dc*(w + N*bv) ; css, cbar
__global__ __launch_bounds__(512) void k_wcc(
    const float* __restrict__ Wv, const float* __restrict__ sv,
    const float* __restrict__ rv, const float* __restrict__ bv,
    float* __restrict__ scal, float* __restrict__ wv_, float* __restrict__ cc) {
  int t = threadIdx.x;
  int j4 = t * 4;
  f32x4 sw = {0.f, 0.f, 0.f, 0.f}, sc = {0.f, 0.f, 0.f, 0.f};
  for (int i = 0; i < 256; ++i) {
    f32x4 wrow = *(const f32x4*)&Wv[(size_t)i * HD + j4];
    float svi = sv[i], ri = rv[i];
    #pragma unroll
    for (int u = 0; u < 4; ++u) { sw[u] += wrow[u] * svi; sc[u] += wrow[u] * ri; }
  }
  float ac = scal[5], dc = scal[4];
  f32x4 bvv = *(const f32x4*)&bv[j4];
  f32x4 ccv;
  #pragma unroll
  for (int u = 0; u < 4; ++u)
    ccv[u] = sc[u] + ac * bvv[u] + dc * (sw[u] + 20000.0f * bvv[u]);
  *(f32x4*)&wv_[j4] = sw;
  *(f32x4*)&cc[j4] = ccv;
  float s2 = ccv[0] * ccv[0] + ccv[1] * ccv[1] + ccv[2] * ccv[2] + ccv[3] * ccv[3];
  float s1 = ccv[0] + ccv[1] + ccv[2] + ccv[3];
  WRED(s1); WRED(s2);
  __shared__ float red[16];
  int w = t >> 6;
  if ((t & 63) == 0) { red[w] = s1; red[8 + w] = s2; }
  __syncthreads();
  if (t == 0) {
    float a1 = 0.f, a2 = 0.f;
    #pragma unroll
    for (int u = 0; u < 8; ++u) { a1 += red[u]; a2 += red[8 + u]; }
    scal[6] = a2;
    scal[7] = a1 * (1.0f / 2048.0f);
  }
}

// Gc = Ac @ Wv + tc bv^T + uc (w + N bv)^T
__global__ __launch_bounds__(256) void k_gc(
    const float* __restrict__ Ac, const float* __restrict__ Wv,
    const float* __restrict__ tc, const float* __restrict__ uc,
    const float* __restrict__ wv_, const float* __restrict__ bv,
    float* __restrict__ Gc) {
  __shared__ float At[64][68];
  __shared__ float Bt[64][132];
  int t = threadIdx.x;
  int i0 = blockIdx.x * 64, j0 = blockIdx.y * 128;
  int ti = t >> 5, tj = t & 31;
  float acc[8][4] = {};
  for (int kt = 0; kt < 256; kt += 64) {
    __syncthreads();
    {
      int rr = t >> 2, c16 = (t & 3) * 16;
      #pragma unroll
      for (int c = 0; c < 4; ++c)
        *(f32x4*)&At[rr][c16 + c * 4] = *(const f32x4*)&Ac[(i0 + rr) * 256 + kt + c16 + c * 4];
    }
    {
      int rr = t >> 2, c32 = (t & 3) * 32;
      #pragma unroll
      for (int c = 0; c < 8; ++c)
        *(f32x4*)&Bt[rr][c32 + c * 4] = *(const f32x4*)&Wv[(size_t)(kt + rr) * HD + j0 + c32 + c * 4];
    }
    __syncthreads();
    #pragma unroll 8
    for (int k2 = 0; k2 < 64; ++k2) {
      float a[8];
      #pragma unroll
      for (int u = 0; u < 8; ++u) a[u] = At[ti * 8 + u][k2];
      f32x4 b = *(const f32x4*)&Bt[k2][tj * 4];
      #pragma unroll
      for (int u = 0; u < 8; ++u)
        #pragma unroll
        for (int v = 0; v < 4; ++v) acc[u][v] += a[u] * b[v];
    }
  }
  int j = j0 + tj * 4;
  f32x4 wv4 = *(const f32x4*)&wv_[j];
  f32x4 bv4 = *(const f32x4*)&bv[j];
  #pragma unroll
  for (int u = 0; u < 8; ++u) {
    int i = i0 + ti * 8 + u;
    float tci = tc[i], uci = uc[i];
    f32x4 o;
    #pragma unroll
    for (int v = 0; v < 4; ++v)
      o[v] = acc[u][v] + tci * bv4[v] + uci * (wv4[v] + 20000.0f * bv4[v]);
    *(f32x4*)&Gc[(size_t)i * HD + j] = o;
  }
}

// gm, m2 -> Bbt rows 512/513 (bf16); css/cbar; zero Bbt rows 514..527
__global__ __launch_bounds__(256) void k_scal2(
    const float* __restrict__ Gc, const float* __restrict__ cc,
    unsigned short* __restrict__ Bbt, float* __restrict__ scal) {
  int b = blockIdx.x, t = threadIdx.x, lane = t & 63, w = t >> 6;
  if (b < 16) {
    int rb = b * 16 + w * 4;
    for (int q2 = 0; q2 < 4; ++q2) {
      int row = rb + q2;
      float s1 = 0.f, s2 = 0.f;
      #pragma unroll
      for (int c = 0; c < 8; ++c) {
        int kk2 = c * 256 + lane * 4;
        f32x4 g4 = *(const f32x4*)&Gc[(size_t)row * HD + kk2];
        f32x4 c4v = *(const f32x4*)&cc[kk2];
        #pragma unroll
        for (int u = 0; u < 4; ++u) { s1 += g4[u]; s2 += g4[u] * c4v[u]; }
      }
      WRED(s1); WRED(s2);
      if (lane == 0) {
        Bbt[512 * 256 + row] = f2bf(s1 * (1.0f / 2048.0f));
        Bbt[513 * 256 + row] = f2bf(s2);
      }
    }
  } else {
    float s1 = 0.f, s2 = 0.f;
    #pragma unroll
    for (int c = 0; c < 2; ++c) {
      f32x4 v = *(const f32x4*)&cc[t * 8 + c * 4];
      #pragma unroll
      for (int u = 0; u < 4; ++u) { s1 += v[u]; s2 += v[u] * v[u]; }
    }
    WRED(s1); WRED(s2);
    __shared__ float red[8];
    if (lane == 0) { red[w] = s1; red[4 + w] = s2; }
    __syncthreads();
    if (t == 0) {
      scal[6] = red[4] + red[5] + red[6] + red[7];
      scal[7] = (red[0] + red[1] + red[2] + red[3]) * (1.0f / 2048.0f);
    }
    for (int idx = t; idx < 14 * 256; idx += 256) Bbt[514 * 256 + idx] = 0;
  }
}

// M_part[z] = Gc Gc^T (split-K fp32)
__global__ __launch_bounds__(256) void k_m(const float* __restrict__ Gc,
                                           float* __restrict__ M_part) {
  __shared__ float Gi[32][68];
  __shared__ float Gj[32][68];
  int t = threadIdx.x;
  int i0 = blockIdx.x * 32, j0 = blockIdx.y * 32, z = blockIdx.z;
  int ti = t >> 4, tj = t & 15;
  float acc[2][2] = {};
  for (int kt = 0; kt < 512; kt += 64) {
    int kb = z * 512 + kt;
    __syncthreads();
    {
      int rr = t >> 3, c8 = (t & 7) * 8;
      *(f32x4*)&Gi[rr][c8] = *(const f32x4*)&Gc[(size_t)(i0 + rr) * HD + kb + c8];
      *(f32x4*)&Gi[rr][c8 + 4] = *(const f32x4*)&Gc[(size_t)(i0 + rr) * HD + kb + c8 + 4];
      *(f32x4*)&Gj[rr][c8] = *(const f32x4*)&Gc[(size_t)(j0 + rr) * HD + kb + c8];
      *(f32x4*)&Gj[rr][c8 + 4] = *(const f32x4*)&Gc[(size_t)(j0 + rr) * HD + kb + c8 + 4];
    }
    __syncthreads();
    #pragma unroll 8
    for (int k2 = 0; k2 < 64; ++k2) {
      float a0 = Gi[ti * 2][k2], a1 = Gi[ti * 2 + 1][k2];
      float b0 = Gj[tj * 2][k2], b1 = Gj[tj * 2 + 1][k2];
      acc[0][0] += a0 * b0; acc[0][1] += a0 * b1;
      acc[1][0] += a1 * b0; acc[1][1] += a1 * b1;
    }
  }
  #pragma unroll
  for (int u = 0; u < 2; ++u)
    #pragma unroll
    for (int v = 0; v < 2; ++v)
      M_part[(size_t)z * 65536 + (i0 + ti * 2 + u) * 256 + j0 + tj * 2 + v] = acc[u][v];
}

// Hc'_part[z] = A' @ (Wo*(1-li)), A' rows: Gc*g | g | cc*g | lnb | 0-pad (288 rows)
__global__ __launch_bounds__(256) void k_hc(
    const float* __restrict__ Gc, const float* __restrict__ Wo,
    const float* __restrict__ g, const float* __restrict__ cc,
    const float* __restrict__ lnb, const float* __restrict__ scal,
    float* __restrict__ Hc_part) {
  __shared__ float At[32][68];
  __shared__ float Bt[64][68];
  int t = threadIdx.x;
  int i0 = blockIdx.x * 32, j0 = blockIdx.y * 64, z = blockIdx.z;
  float s2 = scal[2];
  int ti = t >> 5, tj = t & 31;
  float acc[4][2] = {};
  for (int kt = 0; kt < 512; kt += 64) {
    int kb = z * 512 + kt;
    __syncthreads();
    {
      int rr = t >> 3, c8 = (t & 7) * 8, gi = i0 + rr;
      #pragma unroll
      for (int h = 0; h < 8; h += 4) {
        f32x4 g4 = *(const f32x4*)&g[kb + c8 + h];
        f32x4 a;
        if (gi < 256) {
          f32x4 gg = *(const f32x4*)&Gc[(size_t)gi * HD + kb + c8 + h];
          #pragma unroll
          for (int u = 0; u < 4; ++u) a[u] = gg[u] * g4[u];
        } else if (gi == 256) {
          a = g4;
        } else if (gi == 257) {
          f32x4 c4v = *(const f32x4*)&cc[kb + c8 + h];
          #pragma unroll
          for (int u = 0; u < 4; ++u) a[u] = c4v[u] * g4[u];
        } else if (gi == 258) {
          a = *(const f32x4*)&lnb[kb + c8 + h];
        } else {
          a = (f32x4){0.f, 0.f, 0.f, 0.f};
        }
        *(f32x4*)&At[rr][c8 + h] = a;
      }
    }
    {
      int rr = t >> 2, c16 = (t & 3) * 16;
      #pragma unroll
      for (int c = 0; c < 4; ++c) {
        f32x4 b = *(const f32x4*)&Wo[(size_t)(kb + rr) * 256 + j0 + c16 + c * 4];
        #pragma unroll
        for (int u = 0; u < 4; ++u) b[u] *= s2;
        *(f32x4*)&Bt[rr][c16 + c * 4] = b;
      }
    }
    __syncthreads();
    #pragma unroll 8
    for (int k2 = 0; k2 < 64; ++k2) {
      float a[4];
      #pragma unroll
      for (int u = 0; u < 4; ++u) a[u] = At[ti * 4 + u][k2];
      f32x2 b2 = *(const f32x2*)&Bt[k2][tj * 2];
      #pragma unroll
      for (int u = 0; u < 4; ++u) { acc[u][0] += a[u] * b2[0]; acc[u][1] += a[u] * b2[1]; }
    }
  }
  #pragma unroll
  for (int u = 0; u < 4; ++u) {
    Hc_part[(size_t)z * 73728 + (i0 + ti * 4 + u) * 256 + j0 + tj * 2] = acc[u][0];
    Hc_part[(size_t)z * 73728 + (i0 + ti * 4 + u) * 256 + j0 + tj * 2 + 1] = acc[u][1];
  }
}

// reduce M/Hc partials -> Bbt (transposed, bf16); vectors wbar/hc/bc
__global__ __launch_bounds__(256) void k_red2(
    const float* __restrict__ M_part, const float* __restrict__ Hc_part,
    const float* __restrict__ bo, unsigned short* __restrict__ Bbt,
    float* __restrict__ wbar, float* __restrict__ hcv, float* __restrict__ bcv) {
  int bi = blockIdx.x, z2 = blockIdx.y, t = threadIdx.x;
  if (z2 == 2) {
    if (bi != 0) return;
    float s0 = 0.f, s1 = 0.f, s2 = 0.f;
    #pragma unroll
    for (int z = 0; z < 4; ++z) {
      s0 += Hc_part[(size_t)z * 73728 + 256 * 256 + t];
      s1 += Hc_part[(size_t)z * 73728 + 257 * 256 + t];
      s2 += Hc_part[(size_t)z * 73728 + 258 * 256 + t];
    }
    wbar[t] = s0; hcv[t] = s1; bcv[t] = s2 + bo[t];
    return;
  }
  __shared__ unsigned short T[64][256];
  const float* src = z2 ? Hc_part : M_part;
  const size_t sp = z2 ? 73728 : 65536;
  const int base = z2 ? 256 : 0;
  for (int ii = 0; ii < 64; ++ii) {
    int i = bi * 64 + ii;
    float s = 0.f;
    #pragma unroll
    for (int z = 0; z < 4; ++z) s += src[z * sp + i * 256 + t];
    T[ii][t] = f2bf(s);
  }
  __syncthreads();
  #pragma unroll
  for (int c = 0; c < 64; c += 8) {
    u16x8 o;
    #pragma unroll
    for (int u = 0; u < 8; ++u) o[u] = T[c + u][t];
    *(u16x8*)&Bbt[(size_t)(base + t) * 256 + bi * 64 + c] = o;
  }
}

// fused final: y|z|mu|m2 = q @ Bbt^T, then LN-stats + output epilogue
__global__ __launch_bounds__(256) void k_out(
    const float* __restrict__ q, const unsigned short* __restrict__ Bbt,
    const float* __restrict__ hcv, const float* __restrict__ wbar,
    const float* __restrict__ bcv, const float* __restrict__ scal,
    float* __restrict__ out) {
  __shared__ unsigned short As[32 * 264];
  __shared__ float sqp[2][32];
  __shared__ float muL[32], m2L[32];
  const int t = threadIdx.x, lane = t & 63, wave = t >> 6;
  const int row0 = blockIdx.x * 32;
  const int r15 = lane & 15, kg = lane >> 4;
  {
    int r = t >> 3;
    #pragma unroll
    for (int ci = 0; ci < 8; ++ci) {
      int col = ci * 32 + (t & 7) * 4;
      f32x4 v = *(const f32x4*)&q[(size_t)(row0 + r) * HIW + col];
      u16x4 o;
      #pragma unroll
      for (int u = 0; u < 4; ++u) o[u] = f2bf(v[u]);
      *(u16x4*)&As[r * 264 + col] = o;
    }
  }
  __syncthreads();
  const int wc = wave * 128;
  f32x4 acc[2][9];
  #pragma unroll
  for (int m = 0; m < 2; ++m)
    #pragma unroll
    for (int n = 0; n < 9; ++n) acc[m][n] = (f32x4){0.f, 0.f, 0.f, 0.f};
  #pragma unroll
  for (int ko = 0; ko < 8; ++ko) {
    bf16x8 af0 = *(const bf16x8*)&As[r15 * 264 + ko * 32 + kg * 8];
    bf16x8 af1 = *(const bf16x8*)&As[(16 + r15) * 264 + ko * 32 + kg * 8];
    #pragma unroll
    for (int ni = 0; ni < 9; ++ni) {
      if (ni == 8 && wave != 3) continue;
      int colb = wc + ni * 16 + r15;
      bf16x8 bfr = *(const bf16x8*)&Bbt[(size_t)colb * 256 + ko * 32 + kg * 8];
      acc[0][ni] = __builtin_amdgcn_mfma_f32_16x16x32_bf16(af0, bfr, acc[0][ni], 0, 0, 0);
      acc[1][ni] = __builtin_amdgcn_mfma_f32_16x16x32_bf16(af1, bfr, acc[1][ni], 0, 0, 0);
    }
  }
  // phase 1: per-row partial dots
  if (wave < 2) {
    #pragma unroll
    for (int m = 0; m < 2; ++m)
      #pragma unroll
      for (int r = 0; r < 4; ++r) {
        int rowl = m * 16 + kg * 4 + r;
        float p = 0.f;
        #pragma unroll
        for (int ni = 0; ni < 8; ++ni) {
          int col = wc + ni * 16 + r15;
          p += acc[m][ni][r] * bf2f(As[rowl * 264 + col]);
        }
        p += __shfl_xor(p, 1); p += __shfl_xor(p, 2);
        p += __shfl_xor(p, 4); p += __shfl_xor(p, 8);
        if (r15 == 0) sqp[wave][rowl] = p;
      }
  }
  if (wave == 3) {
    #pragma unroll
    for (int m = 0; m < 2; ++m)
      #pragma unroll
      for (int r = 0; r < 4; ++r) {
        int rowl = m * 16 + kg * 4 + r;
        if (r15 == 0) muL[rowl] = acc[m][8][r];
        if (r15 == 1) m2L[rowl] = acc[m][8][r];
      }
  }
  __syncthreads();
  if (wave >= 2) {
    const float css = scal[6], cbar = scal[7];
    #pragma unroll
    for (int m = 0; m < 2; ++m)
      #pragma unroll
      for (int r = 0; r < 4; ++r) {
        int rowl = m * 16 + kg * 4 + r;
        float mu = muL[rowl] + cbar;
        float ss = sqp[0][rowl] + sqp[1][rowl] + 2.0f * m2L[rowl] + css;
        float var = ss * (1.0f / 2048.0f) - mu * mu;
        float rstd = rsqrtf(var + 1e-5f);
        int grow = row0 + rowl;
        #pragma unroll
        for (int ni = 0; ni < 8; ++ni) {
          int oc = (wc - 256) + ni * 16 + r15;
          float zv = acc[m][ni][r] + hcv[oc];
          out[(size_t)grow * HIW + oc] = rstd * (zv - mu * wbar[oc]) + bcv[oc];
        }
      }
  }
}

extern "C" void kernel_launch(void* const* d_in, const int* in_sizes, int n_in,
                              void* d_out, int out_size, void* d_ws, size_t ws_size,
                              hipStream_t stream) {
  const float* q   = (const float*)d_in[0];
  const float* k   = (const float*)d_in[1];
  const float* v   = (const float*)d_in[2];
  const int* layer = (const int*)d_in[3];
  const float* Wq1 = (const float*)d_in[4];  const float* bq1 = (const float*)d_in[5];
  const float* Wk1 = (const float*)d_in[6];  const float* bk1 = (const float*)d_in[7];
  const float* Wq2 = (const float*)d_in[8];  const float* bq2 = (const float*)d_in[9];
  const float* Wk2 = (const float*)d_in[10]; const float* bk2 = (const float*)d_in[11];
  const float* Wv  = (const float*)d_in[12]; const float* bv  = (const float*)d_in[13];
  const float* lng = (const float*)d_in[14]; const float* lnb = (const float*)d_in[15];
  const float* Wo  = (const float*)d_in[16]; const float* bo  = (const float*)d_in[17];
  const float* lq1 = (const float*)d_in[18]; const float* lk1 = (const float*)d_in[19];
  const float* lq2 = (const float*)d_in[20]; const float* lk2 = (const float*)d_in[21];

  char* p = (char*)d_ws;
  float* S_part = (float*)p;  p += (size_t)32 * 65536 * 4;
  float* skp = (float*)p;     p += 160 * 256 * 4;
  float* svp = (float*)p;     p += 160 * 256 * 4;
  float* Pc_part = (float*)p; p += (size_t)4 * 65536 * 4;
  float* S  = (float*)p;      p += 65536 * 4;
  float* ST = (float*)p;      p += 65536 * 4;
  float* Pc = (float*)p;      p += 65536 * 4;
  float* sk = (float*)p;      p += 1024;
  float* sv = (float*)p;      p += 1024;
  float* gc = (float*)p;      p += 1024;
  float* uc = (float*)p;      p += 1024;
  float* tc = (float*)p;      p += 1024;
  float* rv = (float*)p;      p += 1024;
  float* wv_ = (float*)p;     p += 2048 * 4;
  float* cc  = (float*)p;     p += 2048 * 4;
  float* Ac  = (float*)p;     p += 65536 * 4;
  float* Gc  = (float*)p;     p += (size_t)2048 * 256 * 4;  // 256 rows x 2048 cols
  float* M_part  = (float*)p; p += (size_t)4 * 65536 * 4;
  float* Hc_part = (float*)p; p += (size_t)4 * 288 * 256 * 4;
  unsigned short* Bbt = (unsigned short*)p; p += (size_t)528 * 256 * 2;
  float* wbar = (float*)p;    p += 1024;
  float* hcv  = (float*)p;    p += 1024;
  float* bcv  = (float*)p;    p += 1024;
  float* scal = (float*)p;    p += 256;

  const dim3 b256(256);
  k_lambda<<<dim3(1), b256, 0, stream>>>(lq1, lk1, lq2, lk2, bq1, bk1, bq2, bk2, layer, scal);
  k_colsum<<<dim3(160), b256, 0, stream>>>(k, v, skp, svp);
  k_s<<<dim3(2, 2, 32), b256, 0, stream>>>(k, v, S_part);
  k_pc<<<dim3(2, 2, 4), b256, 0, stream>>>(Wq1, Wk1, Wq2, Wk2, scal, Pc_part);
  k_sred<<<dim3(513), b256, 0, stream>>>(S_part, Pc_part, skp, svp, S, ST, Pc, sk, sv);
  k_mv<<<dim3(32), b256, 0, stream>>>(Wk1, Wk2, Wq1, Wq2, bq1, bq2, bk1, bk2, scal, gc, uc);
  k_ac<<<dim3(34), b256, 0, stream>>>(Pc, S, gc, sk, Ac, tc, rv, scal);
  k_wcc<<<dim3(1), dim3(512), 0, stream>>>(Wv, sv, rv, bv, scal, wv_, cc);
  k_gc<<<dim3(4, 16), b256, 0, stream>>>(Ac, Wv, tc, uc, wv_, bv, Gc);
  k_scal2<<<dim3(17), b256, 0, stream>>>(Gc, cc, Bbt, scal);
  k_m<<<dim3(8, 8, 4), b256, 0, stream>>>(Gc, M_part);
  k_hc<<<dim3(9, 4, 4), b256, 0, stream>>>(Gc, Wo, lng, cc, lnb, scal, Hc_part);
  k_red2<<<dim3(4, 3), b256, 0, stream>>>(M_part, Hc_part, bo, Bbt, wbar, hcv, bcv);
  k_out<<<dim3(625), b256, 0, stream>>>(q, Bbt, hcv, wbar, bcv, scal, (float*)d_out);
}

// Round 4
// 228.516 us; speedup vs baseline: 1.5478x; 1.5478x over previous
//
#include <hip/hip_runtime.h>
#include <stdint.h>

typedef __bf16 bf16x8 __attribute__((ext_vector_type(8)));
typedef float f32x4 __attribute__((ext_vector_type(4)));
typedef float f32x2 __attribute__((ext_vector_type(2)));
typedef unsigned short u16x4 __attribute__((ext_vector_type(4)));
typedef unsigned short u16x8 __attribute__((ext_vector_type(8)));

#define NTOK 20000
#define HIW  256
#define HD   2048

static __device__ __forceinline__ unsigned short f2bf(float f) {
  union { float f; unsigned u; } c; c.f = f;
  unsigned u = c.u + (0x7fffu + ((c.u >> 16) & 1u));   // RNE
  return (unsigned short)(u >> 16);
}
static __device__ __forceinline__ float bf2f(unsigned short h) {
  union { unsigned u; float f; } c; c.u = ((unsigned)h) << 16;
  return c.f;
}

#define WRED(x) { x += __shfl_xor(x,32); x += __shfl_xor(x,16); x += __shfl_xor(x,8); \
                  x += __shfl_xor(x,4);  x += __shfl_xor(x,2);  x += __shfl_xor(x,1); }

// scal: 0=lam 1=-lam 2=1-li 3=li 4=dc 5=alpha_c 6=css 7=cbar
__global__ __launch_bounds__(256) void k_lambda(
    const float* __restrict__ lq1, const float* __restrict__ lk1,
    const float* __restrict__ lq2, const float* __restrict__ lk2,
    const float* __restrict__ bq1, const float* __restrict__ bk1,
    const float* __restrict__ bq2, const float* __restrict__ bk2,
    const int* __restrict__ layer, float* __restrict__ scal) {
  int t = threadIdx.x;
  float p1 = lq1[t] * lk1[t], p2 = lq2[t] * lk2[t];
  float d1 = 0.f, d2 = 0.f;
  #pragma unroll
  for (int u = 0; u < 8; ++u) {
    d1 += bq1[t * 8 + u] * bk1[t * 8 + u];
    d2 += bq2[t * 8 + u] * bk2[t * 8 + u];
  }
  WRED(p1); WRED(p2); WRED(d1); WRED(d2);
  __shared__ float red[16];
  int w = t >> 6;
  if ((t & 63) == 0) { red[w] = p1; red[4 + w] = p2; red[8 + w] = d1; red[12 + w] = d2; }
  __syncthreads();
  if (t == 0) {
    float s1 = red[0] + red[1] + red[2] + red[3];
    float s2 = red[4] + red[5] + red[6] + red[7];
    float dd1 = red[8] + red[9] + red[10] + red[11];
    float dd2 = red[12] + red[13] + red[14] + red[15];
    float li = 0.8f - 0.6f * expf(-0.3f * (float)layer[0]);
    float lam = expf(s1) - expf(s2) + li;
    scal[0] = lam; scal[1] = -lam; scal[2] = 1.0f - li; scal[3] = li;
    scal[4] = dd1 - lam * dd2;
  }
}

// S_part[z] += k^T v over n-chunk z (hi/lo split bf16 MFMA, fp32-quality).
// LDS 16B-block XOR swizzle kills the transpose-write bank conflicts.
// Diagonal blocks (bx==by) also accumulate column sums of k and v.
__global__ __launch_bounds__(256) void k_s(
    const float* __restrict__ kk, const float* __restrict__ vv,
    float* __restrict__ S_part, float* __restrict__ skp, float* __restrict__ svp) {
  __shared__ unsigned short SH[4 * 128 * 72];
  unsigned short* Ahi = SH;
  unsigned short* Alo = SH + 128 * 72;
  unsigned short* Bhi = SH + 2 * 128 * 72;
  unsigned short* Blo = SH + 3 * 128 * 72;
  const int t = threadIdx.x, lane = t & 63, wave = t >> 6;
  const int i0 = blockIdx.x * 128, j0 = blockIdx.y * 128, z = blockIdx.z;
  const bool diag = (blockIdx.x == blockIdx.y);
  const int wr = (wave >> 1) * 64, wc = (wave & 1) * 64;
  const int r15 = lane & 15;
  const int n_lo = z * 313;
  const int cnt = (NTOK - n_lo < 313) ? (NTOK - n_lo) : 313;
  f32x4 acc[4][4];
  #pragma unroll
  for (int m = 0; m < 4; ++m)
    #pragma unroll
    for (int n = 0; n < 4; ++n) acc[m][n] = (f32x4){0.f, 0.f, 0.f, 0.f};
  f32x4 ksum = {0.f, 0.f, 0.f, 0.f}, vsum = {0.f, 0.f, 0.f, 0.f};
  const int r0 = t >> 5, c4 = (t & 31) * 4;
  const int wkey = t & 7;   // ((c4+u)>>2)&7 for u in 0..3

  for (int kt = 0; kt < 5; ++kt) {
    __syncthreads();
    #pragma unroll
    for (int it = 0; it < 8; ++it) {
      const int nn = kt * 64 + it * 8 + r0;
      const bool valid = nn < cnt;
      const int gn = n_lo + nn;
      f32x4 a = {0.f, 0.f, 0.f, 0.f}, b = {0.f, 0.f, 0.f, 0.f};
      if (valid) {
        a = *(const f32x4*)&kk[(size_t)gn * HIW + i0 + c4];
        b = *(const f32x4*)&vv[(size_t)gn * HIW + j0 + c4];
      }
      ksum += a; vsum += b;
      const int cb = ((it ^ wkey) << 3) + r0;   // swizzled col
      #pragma unroll
      for (int u = 0; u < 4; ++u) {
        unsigned short h = f2bf(a[u]);
        Ahi[(c4 + u) * 72 + cb] = h;
        Alo[(c4 + u) * 72 + cb] = f2bf(a[u] - bf2f(h));
        h = f2bf(b[u]);
        Bhi[(c4 + u) * 72 + cb] = h;
        Blo[(c4 + u) * 72 + cb] = f2bf(b[u] - bf2f(h));
      }
    }
    __syncthreads();
    #pragma unroll
    for (int ks = 0; ks < 2; ++ks) {
      const int kb = ks * 4 + (lane >> 4);
      bf16x8 ah[4], al[4], bh[4], bl[4];
      #pragma unroll
      for (int m = 0; m < 4; ++m) {
        const int row = wr + m * 16 + r15;
        const int off = row * 72 + ((kb ^ ((row >> 2) & 7)) << 3);
        ah[m] = *(const bf16x8*)&Ahi[off];
        al[m] = *(const bf16x8*)&Alo[off];
      }
      #pragma unroll
      for (int n = 0; n < 4; ++n) {
        const int row = wc + n * 16 + r15;
        const int off = row * 72 + ((kb ^ ((row >> 2) & 7)) << 3);
        bh[n] = *(const bf16x8*)&Bhi[off];
        bl[n] = *(const bf16x8*)&Blo[off];
      }
      #pragma unroll
      for (int m = 0; m < 4; ++m)
        #pragma unroll
        for (int n = 0; n < 4; ++n) {
          acc[m][n] = __builtin_amdgcn_mfma_f32_16x16x32_bf16(ah[m], bh[n], acc[m][n], 0, 0, 0);
          acc[m][n] = __builtin_amdgcn_mfma_f32_16x16x32_bf16(ah[m], bl[n], acc[m][n], 0, 0, 0);
          acc[m][n] = __builtin_amdgcn_mfma_f32_16x16x32_bf16(al[m], bh[n], acc[m][n], 0, 0, 0);
        }
    }
  }
  const int rg = (lane >> 4) * 4;
  #pragma unroll
  for (int m = 0; m < 4; ++m)
    #pragma unroll
    for (int n = 0; n < 4; ++n)
      #pragma unroll
      for (int r = 0; r < 4; ++r)
        S_part[(size_t)z * 65536 + (i0 + wr + m * 16 + rg + r) * 256 + (j0 + wc + n * 16 + r15)] =
            acc[m][n][r];

  if (diag) {
    __syncthreads();                 // all LDS reads done -> safe to reuse
    float* red = (float*)SH;         // [8][128] ksum | [8][128] vsum
    *(f32x4*)&red[r0 * 128 + c4] = ksum;
    *(f32x4*)&red[1024 + r0 * 128 + c4] = vsum;
    __syncthreads();
    const int col = t & 127, which = t >> 7;
    float s = 0.f;
    #pragma unroll
    for (int r = 0; r < 8; ++r) s += red[which * 1024 + r * 128 + col];
    if (which == 0) skp[z * 256 + i0 + col] = s;
    else            svp[z * 256 + j0 + col] = s;
  }
}

// Pc_part[z] = Wq1 Wk1^T - lam Wq2 Wk2^T (split-K over 2048, hi/lo MFMA)
__global__ __launch_bounds__(256) void k_pc(
    const float* __restrict__ Wq1, const float* __restrict__ Wk1,
    const float* __restrict__ Wq2, const float* __restrict__ Wk2,
    const float* __restrict__ scal, float* __restrict__ Pc_part) {
  __shared__ unsigned short SH[4 * 128 * 72];
  unsigned short* Ahi = SH;
  unsigned short* Alo = SH + 128 * 72;
  unsigned short* Bhi = SH + 2 * 128 * 72;
  unsigned short* Blo = SH + 3 * 128 * 72;
  const int t = threadIdx.x, lane = t & 63, wave = t >> 6;
  const int i0 = blockIdx.x * 128, j0 = blockIdx.y * 128, z = blockIdx.z;
  const int wr = (wave >> 1) * 64, wc = (wave & 1) * 64;
  const int r15 = lane & 15, kg = (lane >> 4) * 8;
  const float nlam = scal[1];
  f32x4 acc[4][4];
  #pragma unroll
  for (int m = 0; m < 4; ++m)
    #pragma unroll
    for (int n = 0; n < 4; ++n) acc[m][n] = (f32x4){0.f, 0.f, 0.f, 0.f};
  const int srow = t >> 1, sh = (t & 1) * 32;
  for (int pair = 0; pair < 2; ++pair) {
    const float* Wa = pair ? Wq2 : Wq1;
    const float* Wb = pair ? Wk2 : Wk1;
    const float asc = pair ? nlam : 1.0f;
    for (int kt = 0; kt < 2; ++kt) {
      const int kb = z * 128 + kt * 64 + sh;
      __syncthreads();
      #pragma unroll
      for (int c = 0; c < 8; ++c) {
        f32x4 a = *(const f32x4*)&Wa[(size_t)(i0 + srow) * HD + kb + c * 4];
        f32x4 b = *(const f32x4*)&Wb[(size_t)(j0 + srow) * HD + kb + c * 4];
        #pragma unroll
        for (int u = 0; u < 4; ++u) {
          float av = a[u] * asc;
          unsigned short h = f2bf(av);
          Ahi[srow * 72 + sh + c * 4 + u] = h;
          Alo[srow * 72 + sh + c * 4 + u] = f2bf(av - bf2f(h));
          h = f2bf(b[u]);
          Bhi[srow * 72 + sh + c * 4 + u] = h;
          Blo[srow * 72 + sh + c * 4 + u] = f2bf(b[u] - bf2f(h));
        }
      }
      __syncthreads();
      #pragma unroll
      for (int ks = 0; ks < 2; ++ks) {
        const int ko = ks * 32 + kg;
        bf16x8 ah[4], al[4], bh[4], bl[4];
        #pragma unroll
        for (int m = 0; m < 4; ++m) {
          ah[m] = *(const bf16x8*)&Ahi[(wr + m * 16 + r15) * 72 + ko];
          al[m] = *(const bf16x8*)&Alo[(wr + m * 16 + r15) * 72 + ko];
        }
        #pragma unroll
        for (int n = 0; n < 4; ++n) {
          bh[n] = *(const bf16x8*)&Bhi[(wc + n * 16 + r15) * 72 + ko];
          bl[n] = *(const bf16x8*)&Blo[(wc + n * 16 + r15) * 72 + ko];
        }
        #pragma unroll
        for (int m = 0; m < 4; ++m)
          #pragma unroll
          for (int n = 0; n < 4; ++n) {
            acc[m][n] = __builtin_amdgcn_mfma_f32_16x16x32_bf16(ah[m], bh[n], acc[m][n], 0, 0, 0);
            acc[m][n] = __builtin_amdgcn_mfma_f32_16x16x32_bf16(ah[m], bl[n], acc[m][n], 0, 0, 0);
            acc[m][n] = __builtin_amdgcn_mfma_f32_16x16x32_bf16(al[m], bh[n], acc[m][n], 0, 0, 0);
          }
      }
    }
  }
  const int rg = (lane >> 4) * 4;
  #pragma unroll
  for (int m = 0; m < 4; ++m)
    #pragma unroll
    for (int n = 0; n < 4; ++n)
      #pragma unroll
      for (int r = 0; r < 4; ++r)
        Pc_part[(size_t)z * 65536 + (i0 + wr + m * 16 + rg + r) * 256 + (j0 + wc + n * 16 + r15)] =
            acc[m][n][r];
}

// reductions + (merged) k_mv: gc = Wk1 bq1 - lam Wk2 bq2 ; uc = Wq1 bk1 - lam Wq2 bk2
__global__ __launch_bounds__(256) void k_sred(
    const float* __restrict__ S_part, const float* __restrict__ Pc_part,
    const float* __restrict__ skp, const float* __restrict__ svp,
    float* __restrict__ S, float* __restrict__ Pc,
    float* __restrict__ sk, float* __restrict__ sv,
    const float* __restrict__ Wk1, const float* __restrict__ Wk2,
    const float* __restrict__ Wq1, const float* __restrict__ Wq2,
    const float* __restrict__ bq1, const float* __restrict__ bq2,
    const float* __restrict__ bk1, const float* __restrict__ bk2,
    const float* __restrict__ scal, float* __restrict__ gc, float* __restrict__ uc) {
  int b = blockIdx.x, t = threadIdx.x;
  if (b < 256) {
    int idx = b * 256 + t;
    float s = 0.f;
    for (int z = 0; z < 64; ++z) s += S_part[(size_t)z * 65536 + idx];
    S[idx] = s;
  } else if (b < 512) {
    int idx = (b - 256) * 256 + t;
    float s = 0.f;
    #pragma unroll
    for (int z = 0; z < 16; ++z) s += Pc_part[(size_t)z * 65536 + idx];
    Pc[idx] = s;
  } else if (b < 514) {
    const float* src = (b == 512) ? skp : svp;
    float s = 0.f;
    for (int z = 0; z < 64; ++z) s += src[z * 256 + t];
    if (b == 512) sk[t] = s; else sv[t] = s;
  } else {
    int bb = b - 514, lane = t & 63, w = t >> 6;
    bool dogc = bb < 16;
    const float* A1 = dogc ? Wk1 : Wq1;
    const float* A2 = dogc ? Wk2 : Wq2;
    const float* x1 = dogc ? bq1 : bk1;
    const float* x2 = dogc ? bq2 : bk2;
    float* outv = dogc ? gc : uc;
    float lam = scal[0];
    int rb = (bb & 15) * 16 + w * 4;
    for (int q2 = 0; q2 < 4; ++q2) {
      int row = rb + q2;
      float s1 = 0.f, s2 = 0.f;
      #pragma unroll
      for (int c = 0; c < 8; ++c) {
        int kk2 = c * 256 + lane * 4;
        f32x4 a1 = *(const f32x4*)&A1[(size_t)row * HD + kk2];
        f32x4 a2 = *(const f32x4*)&A2[(size_t)row * HD + kk2];
        f32x4 v1 = *(const f32x4*)&x1[kk2];
        f32x4 v2 = *(const f32x4*)&x2[kk2];
        #pragma unroll
        for (int u = 0; u < 4; ++u) { s1 += a1[u] * v1[u]; s2 += a2[u] * v2[u]; }
      }
      WRED(s1); WRED(s2);
      if (lane == 0) outv[row] = s1 - lam * s2;
    }
  }
}

// Ac = Pc @ S ; tc = Pc @ sk ; r = S^T gc ; alpha_c = gc . sk
__global__ __launch_bounds__(256) void k_ac(
    const float* __restrict__ Pc, const float* __restrict__ S,
    const float* __restrict__ gc, const float* __restrict__ sk,
    float* __restrict__ Ac, float* __restrict__ tc, float* __restrict__ rv,
    float* __restrict__ scal) {
  int b = blockIdx.x, t = threadIdx.x;
  if (b < 32) {
    __shared__ float Pt[32][68];
    __shared__ float St[64][68];
    int i0 = (b >> 2) * 32, j0 = (b & 3) * 64;
    int ti = t >> 5, tj = t & 31;
    float acc[4][2] = {};
    for (int kt = 0; kt < 256; kt += 64) {
      __syncthreads();
      {
        int rr = t >> 3, c8 = (t & 7) * 8;
        *(f32x4*)&Pt[rr][c8] = *(const f32x4*)&Pc[(i0 + rr) * 256 + kt + c8];
        *(f32x4*)&Pt[rr][c8 + 4] = *(const f32x4*)&Pc[(i0 + rr) * 256 + kt + c8 + 4];
      }
      {
        int rr = t >> 2, c16 = (t & 3) * 16;
        #pragma unroll
        for (int c = 0; c < 4; ++c)
          *(f32x4*)&St[rr][c16 + c * 4] = *(const f32x4*)&S[(kt + rr) * 256 + j0 + c16 + c * 4];
      }
      __syncthreads();
      #pragma unroll 8
      for (int k2 = 0; k2 < 64; ++k2) {
        float a[4];
        #pragma unroll
        for (int u = 0; u < 4; ++u) a[u] = Pt[ti * 4 + u][k2];
        f32x2 b2 = *(const f32x2*)&St[k2][tj * 2];
        #pragma unroll
        for (int u = 0; u < 4; ++u) { acc[u][0] += a[u] * b2[0]; acc[u][1] += a[u] * b2[1]; }
      }
    }
    #pragma unroll
    for (int u = 0; u < 4; ++u) {
      Ac[(i0 + ti * 4 + u) * 256 + j0 + tj * 2] = acc[u][0];
      Ac[(i0 + ti * 4 + u) * 256 + j0 + tj * 2 + 1] = acc[u][1];
    }
  } else if (b == 32) {
    int lane = t & 63, w = t >> 6;
    f32x4 sk4 = *(const f32x4*)&sk[lane * 4];
    for (int ii = 0; ii < 64; ++ii) {
      int i = w * 64 + ii;
      f32x4 p4 = *(const f32x4*)&Pc[i * 256 + lane * 4];
      float s = p4[0] * sk4[0] + p4[1] * sk4[1] + p4[2] * sk4[2] + p4[3] * sk4[3];
      WRED(s);
      if (lane == 0) tc[i] = s;
    }
  } else {
    float s = 0.f;
    #pragma unroll 4
    for (int i = 0; i < 256; ++i) s += gc[i] * S[i * 256 + t];
    rv[t] = s;
    if (t < 64) {
      f32x4 g4 = *(const f32x4*)&gc[t * 4];
      f32x4 sk4 = *(const f32x4*)&sk[t * 4];
      float a = g4[0] * sk4[0] + g4[1] * sk4[1] + g4[2] * sk4[2] + g4[3] * sk4[3];
      WRED(a);
      if (t == 0) scal[5] = a;
    }
  }
}

// w = Wv^T sv ; cc = Wv^T r + alpha_c*bv + dc*(w + N*bv)   (16-block parallel)
__global__ __launch_bounds__(256) void k_wcc(
    const float* __restrict__ Wv, const float* __restrict__ sv,
    const float* __restrict__ rv, const float* __restrict__ bv,
    const float* __restrict__ scal, float* __restrict__ wv_, float* __restrict__ cc) {
  __shared__ float red[2][2][128];
  int t = threadIdx.x;
  int j = blockIdx.x * 128 + (t & 127);
  int half = t >> 7;
  float sw = 0.f, sc = 0.f;
  for (int i = half * 128; i < half * 128 + 128; ++i) {
    float w = Wv[(size_t)i * HD + j];
    sw += w * sv[i]; sc += w * rv[i];
  }
  red[half][0][t & 127] = sw; red[half][1][t & 127] = sc;
  __syncthreads();
  if (half == 0) {
    sw += red[1][0][t & 127]; sc += red[1][1][t & 127];
    float ac = scal[5], dc = scal[4];
    float bvv = bv[j];
    wv_[j] = sw;
    cc[j] = sc + ac * bvv + dc * (sw + 20000.0f * bvv);
  }
}

// Gc = Ac @ Wv + tc bv^T + uc (w + N bv)^T
__global__ __launch_bounds__(256) void k_gc(
    const float* __restrict__ Ac, const float* __restrict__ Wv,
    const float* __restrict__ tc, const float* __restrict__ uc,
    const float* __restrict__ wv_, const float* __restrict__ bv,
    float* __restrict__ Gc) {
  __shared__ float At[64][68];
  __shared__ float Bt[64][132];
  int t = threadIdx.x;
  int i0 = blockIdx.x * 64, j0 = blockIdx.y * 128;
  int ti = t >> 5, tj = t & 31;
  float acc[8][4] = {};
  for (int kt = 0; kt < 256; kt += 64) {
    __syncthreads();
    {
      int rr = t >> 2, c16 = (t & 3) * 16;
      #pragma unroll
      for (int c = 0; c < 4; ++c)
        *(f32x4*)&At[rr][c16 + c * 4] = *(const f32x4*)&Ac[(i0 + rr) * 256 + kt + c16 + c * 4];
    }
    {
      int rr = t >> 2, c32 = (t & 3) * 32;
      #pragma unroll
      for (int c = 0; c < 8; ++c)
        *(f32x4*)&Bt[rr][c32 + c * 4] = *(const f32x4*)&Wv[(size_t)(kt + rr) * HD + j0 + c32 + c * 4];
    }
    __syncthreads();
    #pragma unroll 8
    for (int k2 = 0; k2 < 64; ++k2) {
      float a[8];
      #pragma unroll
      for (int u = 0; u < 8; ++u) a[u] = At[ti * 8 + u][k2];
      f32x4 b = *(const f32x4*)&Bt[k2][tj * 4];
      #pragma unroll
      for (int u = 0; u < 8; ++u)
        #pragma unroll
        for (int v = 0; v < 4; ++v) acc[u][v] += a[u] * b[v];
    }
  }
  int j = j0 + tj * 4;
  f32x4 wv4 = *(const f32x4*)&wv_[j];
  f32x4 bv4 = *(const f32x4*)&bv[j];
  #pragma unroll
  for (int u = 0; u < 8; ++u) {
    int i = i0 + ti * 8 + u;
    float tci = tc[i], uci = uc[i];
    f32x4 o;
    #pragma unroll
    for (int v = 0; v < 4; ++v)
      o[v] = acc[u][v] + tci * bv4[v] + uci * (wv4[v] + 20000.0f * bv4[v]);
    *(f32x4*)&Gc[(size_t)i * HD + j] = o;
  }
}

// merged: [0,17) k_scal2 | [17,273) k_m = Gc Gc^T partials | [273,417) k_hc partials
__global__ __launch_bounds__(256) void k_post(
    const float* __restrict__ Gc, const float* __restrict__ cc,
    const float* __restrict__ Wo, const float* __restrict__ g,
    const float* __restrict__ lnb, const float* __restrict__ scal_c,
    unsigned short* __restrict__ Bbt, float* __restrict__ M_part,
    float* __restrict__ Hc_part, float* __restrict__ scal) {
  __shared__ float SMEM[6528];
  int b = blockIdx.x, t = threadIdx.x;
  if (b < 17) {
    int lane = t & 63, w = t >> 6;
    if (b < 16) {
      int rb = b * 16 + w * 4;
      for (int q2 = 0; q2 < 4; ++q2) {
        int row = rb + q2;
        float s1 = 0.f, s2 = 0.f;
        #pragma unroll
        for (int c = 0; c < 8; ++c) {
          int kk2 = c * 256 + lane * 4;
          f32x4 g4 = *(const f32x4*)&Gc[(size_t)row * HD + kk2];
          f32x4 c4v = *(const f32x4*)&cc[kk2];
          #pragma unroll
          for (int u = 0; u < 4; ++u) { s1 += g4[u]; s2 += g4[u] * c4v[u]; }
        }
        WRED(s1); WRED(s2);
        if (lane == 0) {
          Bbt[512 * 256 + row] = f2bf(s1 * (1.0f / 2048.0f));
          Bbt[513 * 256 + row] = f2bf(s2);
        }
      }
    } else {
      float s1 = 0.f, s2 = 0.f;
      #pragma unroll
      for (int c = 0; c < 2; ++c) {
        f32x4 v = *(const f32x4*)&cc[t * 8 + c * 4];
        #pragma unroll
        for (int u = 0; u < 4; ++u) { s1 += v[u]; s2 += v[u] * v[u]; }
      }
      WRED(s1); WRED(s2);
      if (lane == 0) { SMEM[w] = s1; SMEM[4 + w] = s2; }
      __syncthreads();
      if (t == 0) {
        scal[6] = SMEM[4] + SMEM[5] + SMEM[6] + SMEM[7];
        scal[7] = (SMEM[0] + SMEM[1] + SMEM[2] + SMEM[3]) * (1.0f / 2048.0f);
      }
      for (int idx = t; idx < 14 * 256; idx += 256) Bbt[514 * 256 + idx] = 0;
    }
  } else if (b < 273) {
    float (*Gi)[68] = (float(*)[68])SMEM;
    float (*Gj)[68] = (float(*)[68])(SMEM + 32 * 68);
    int idx = b - 17;
    int bx = idx & 7, by = (idx >> 3) & 7, z = idx >> 6;
    int i0 = bx * 32, j0 = by * 32;
    int ti = t >> 4, tj = t & 15;
    float acc[2][2] = {};
    for (int kt = 0; kt < 512; kt += 64) {
      int kb = z * 512 + kt;
      __syncthreads();
      {
        int rr = t >> 3, c8 = (t & 7) * 8;
        *(f32x4*)&Gi[rr][c8] = *(const f32x4*)&Gc[(size_t)(i0 + rr) * HD + kb + c8];
        *(f32x4*)&Gi[rr][c8 + 4] = *(const f32x4*)&Gc[(size_t)(i0 + rr) * HD + kb + c8 + 4];
        *(f32x4*)&Gj[rr][c8] = *(const f32x4*)&Gc[(size_t)(j0 + rr) * HD + kb + c8];
        *(f32x4*)&Gj[rr][c8 + 4] = *(const f32x4*)&Gc[(size_t)(j0 + rr) * HD + kb + c8 + 4];
      }
      __syncthreads();
      #pragma unroll 8
      for (int k2 = 0; k2 < 64; ++k2) {
        float a0 = Gi[ti * 2][k2], a1 = Gi[ti * 2 + 1][k2];
        float b0 = Gj[tj * 2][k2], b1 = Gj[tj * 2 + 1][k2];
        acc[0][0] += a0 * b0; acc[0][1] += a0 * b1;
        acc[1][0] += a1 * b0; acc[1][1] += a1 * b1;
      }
    }
    #pragma unroll
    for (int u = 0; u < 2; ++u)
      #pragma unroll
      for (int v = 0; v < 2; ++v)
        M_part[(size_t)z * 65536 + (i0 + ti * 2 + u) * 256 + j0 + tj * 2 + v] = acc[u][v];
  } else {
    float (*At)[68] = (float(*)[68])SMEM;
    float (*Bt)[68] = (float(*)[68])(SMEM + 32 * 68);
    int idx = b - 273;
    int bx = idx % 9, rem = idx / 9, by = rem & 3, z = rem >> 2;
    int i0 = bx * 32, j0 = by * 64;
    float s2 = scal_c[2];
    int ti = t >> 5, tj = t & 31;
    float acc[4][2] = {};
    for (int kt = 0; kt < 512; kt += 64) {
      int kb = z * 512 + kt;
      __syncthreads();
      {
        int rr = t >> 3, c8 = (t & 7) * 8, gi = i0 + rr;
        #pragma unroll
        for (int h = 0; h < 8; h += 4) {
          f32x4 g4 = *(const f32x4*)&g[kb + c8 + h];
          f32x4 a;
          if (gi < 256) {
            f32x4 gg = *(const f32x4*)&Gc[(size_t)gi * HD + kb + c8 + h];
            #pragma unroll
            for (int u = 0; u < 4; ++u) a[u] = gg[u] * g4[u];
          } else if (gi == 256) {
            a = g4;
          } else if (gi == 257) {
            f32x4 c4v = *(const f32x4*)&cc[kb + c8 + h];
            #pragma unroll
            for (int u = 0; u < 4; ++u) a[u] = c4v[u] * g4[u];
          } else if (gi == 258) {
            a = *(const f32x4*)&lnb[kb + c8 + h];
          } else {
            a = (f32x4){0.f, 0.f, 0.f, 0.f};
          }
          *(f32x4*)&At[rr][c8 + h] = a;
        }
      }
      {
        int rr = t >> 2, c16 = (t & 3) * 16;
        #pragma unroll
        for (int c = 0; c < 4; ++c) {
          f32x4 bb = *(const f32x4*)&Wo[(size_t)(kb + rr) * 256 + j0 + c16 + c * 4];
          #pragma unroll
          for (int u = 0; u < 4; ++u) bb[u] *= s2;
          *(f32x4*)&Bt[rr][c16 + c * 4] = bb;
        }
      }
      __syncthreads();
      #pragma unroll 8
      for (int k2 = 0; k2 < 64; ++k2) {
        float a[4];
        #pragma unroll
        for (int u = 0; u < 4; ++u) a[u] = At[ti * 4 + u][k2];
        f32x2 b2 = *(const f32x2*)&Bt[k2][tj * 2];
        #pragma unroll
        for (int u = 0; u < 4; ++u) { acc[u][0] += a[u] * b2[0]; acc[u][1] += a[u] * b2[1]; }
      }
    }
    #pragma unroll
    for (int u = 0; u < 4; ++u) {
      Hc_part[(size_t)z * 73728 + (i0 + ti * 4 + u) * 256 + j0 + tj * 2] = acc[u][0];
      Hc_part[(size_t)z * 73728 + (i0 + ti * 4 + u) * 256 + j0 + tj * 2 + 1] = acc[u][1];
    }
  }
}

// reduce M/Hc partials -> Bbt (transposed, bf16); vectors wbar/hc/bc
__global__ __launch_bounds__(256) void k_red2(
    const float* __restrict__ M_part, const float* __restrict__ Hc_part,
    const float* __restrict__ bo, unsigned short* __restrict__ Bbt,
    float* __restrict__ wbar, float* __restrict__ hcv, float* __restrict__ bcv) {
  int bi = blockIdx.x, z2 = blockIdx.y, t = threadIdx.x;
  if (z2 == 2) {
    if (bi != 0) return;
    float s0 = 0.f, s1 = 0.f, s2 = 0.f;
    #pragma unroll
    for (int z = 0; z < 4; ++z) {
      s0 += Hc_part[(size_t)z * 73728 + 256 * 256 + t];
      s1 += Hc_part[(size_t)z * 73728 + 257 * 256 + t];
      s2 += Hc_part[(size_t)z * 73728 + 258 * 256 + t];
    }
    wbar[t] = s0; hcv[t] = s1; bcv[t] = s2 + bo[t];
    return;
  }
  __shared__ unsigned short T[64][256];
  const float* src = z2 ? Hc_part : M_part;
  const size_t sp = z2 ? 73728 : 65536;
  const int base = z2 ? 256 : 0;
  for (int ii = 0; ii < 64; ++ii) {
    int i = bi * 64 + ii;
    float s = 0.f;
    #pragma unroll
    for (int z = 0; z < 4; ++z) s += src[z * sp + i * 256 + t];
    T[ii][t] = f2bf(s);
  }
  __syncthreads();
  #pragma unroll
  for (int c = 0; c < 64; c += 8) {
    u16x8 o;
    #pragma unroll
    for (int u = 0; u < 8; ++u) o[u] = T[c + u][t];
    *(u16x8*)&Bbt[(size_t)(base + t) * 256 + bi * 64 + c] = o;
  }
}

// fused final: y|z|mu|m2 = q @ Bbt^T, then LN-stats + output epilogue
__global__ __launch_bounds__(256) void k_out(
    const float* __restrict__ q, const unsigned short* __restrict__ Bbt,
    const float* __restrict__ hcv, const float* __restrict__ wbar,
    const float* __restrict__ bcv, const float* __restrict__ scal,
    float* __restrict__ out) {
  __shared__ unsigned short As[32 * 264];
  __shared__ float sqp[2][32];
  __shared__ float muL[32], m2L[32];
  const int t = threadIdx.x, lane = t & 63, wave = t >> 6;
  const int row0 = blockIdx.x * 32;
  const int r15 = lane & 15, kg = lane >> 4;
  {
    int r = t >> 3;
    #pragma unroll
    for (int ci = 0; ci < 8; ++ci) {
      int col = ci * 32 + (t & 7) * 4;
      f32x4 v = *(const f32x4*)&q[(size_t)(row0 + r) * HIW + col];
      u16x4 o;
      #pragma unroll
      for (int u = 0; u < 4; ++u) o[u] = f2bf(v[u]);
      *(u16x4*)&As[r * 264 + col] = o;
    }
  }
  __syncthreads();
  const int wc = wave * 128;
  f32x4 acc[2][9];
  #pragma unroll
  for (int m = 0; m < 2; ++m)
    #pragma unroll
    for (int n = 0; n < 9; ++n) acc[m][n] = (f32x4){0.f, 0.f, 0.f, 0.f};
  #pragma unroll
  for (int ko = 0; ko < 8; ++ko) {
    bf16x8 af0 = *(const bf16x8*)&As[r15 * 264 + ko * 32 + kg * 8];
    bf16x8 af1 = *(const bf16x8*)&As[(16 + r15) * 264 + ko * 32 + kg * 8];
    #pragma unroll
    for (int ni = 0; ni < 9; ++ni) {
      if (ni == 8 && wave != 3) continue;
      int colb = wc + ni * 16 + r15;
      bf16x8 bfr = *(const bf16x8*)&Bbt[(size_t)colb * 256 + ko * 32 + kg * 8];
      acc[0][ni] = __builtin_amdgcn_mfma_f32_16x16x32_bf16(af0, bfr, acc[0][ni], 0, 0, 0);
      acc[1][ni] = __builtin_amdgcn_mfma_f32_16x16x32_bf16(af1, bfr, acc[1][ni], 0, 0, 0);
    }
  }
  if (wave < 2) {
    #pragma unroll
    for (int m = 0; m < 2; ++m)
      #pragma unroll
      for (int r = 0; r < 4; ++r) {
        int rowl = m * 16 + kg * 4 + r;
        float p = 0.f;
        #pragma unroll
        for (int ni = 0; ni < 8; ++ni) {
          int col = wc + ni * 16 + r15;
          p += acc[m][ni][r] * bf2f(As[rowl * 264 + col]);
        }
        p += __shfl_xor(p, 1); p += __shfl_xor(p, 2);
        p += __shfl_xor(p, 4); p += __shfl_xor(p, 8);
        if (r15 == 0) sqp[wave][rowl] = p;
      }
  }
  if (wave == 3) {
    #pragma unroll
    for (int m = 0; m < 2; ++m)
      #pragma unroll
      for (int r = 0; r < 4; ++r) {
        int rowl = m * 16 + kg * 4 + r;
        if (r15 == 0) muL[rowl] = acc[m][8][r];
        if (r15 == 1) m2L[rowl] = acc[m][8][r];
      }
  }
  __syncthreads();
  if (wave >= 2) {
    const float css = scal[6], cbar = scal[7];
    #pragma unroll
    for (int m = 0; m < 2; ++m)
      #pragma unroll
      for (int r = 0; r < 4; ++r) {
        int rowl = m * 16 + kg * 4 + r;
        float mu = muL[rowl] + cbar;
        float ss = sqp[0][rowl] + sqp[1][rowl] + 2.0f * m2L[rowl] + css;
        float var = ss * (1.0f / 2048.0f) - mu * mu;
        float rstd = rsqrtf(var + 1e-5f);
        int grow = row0 + rowl;
        #pragma unroll
        for (int ni = 0; ni < 8; ++ni) {
          int oc = (wc - 256) + ni * 16 + r15;
          float zv = acc[m][ni][r] + hcv[oc];
          out[(size_t)grow * HIW + oc] = rstd * (zv - mu * wbar[oc]) + bcv[oc];
        }
      }
  }
}

extern "C" void kernel_launch(void* const* d_in, const int* in_sizes, int n_in,
                              void* d_out, int out_size, void* d_ws, size_t ws_size,
                              hipStream_t stream) {
  const float* q   = (const float*)d_in[0];
  const float* k   = (const float*)d_in[1];
  const float* v   = (const float*)d_in[2];
  const int* layer = (const int*)d_in[3];
  const float* Wq1 = (const float*)d_in[4];  const float* bq1 = (const float*)d_in[5];
  const float* Wk1 = (const float*)d_in[6];  const float* bk1 = (const float*)d_in[7];
  const float* Wq2 = (const float*)d_in[8];  const float* bq2 = (const float*)d_in[9];
  const float* Wk2 = (const float*)d_in[10]; const float* bk2 = (const float*)d_in[11];
  const float* Wv  = (const float*)d_in[12]; const float* bv  = (const float*)d_in[13];
  const float* lng = (const float*)d_in[14]; const float* lnb = (const float*)d_in[15];
  const float* Wo  = (const float*)d_in[16]; const float* bo  = (const float*)d_in[17];
  const float* lq1 = (const float*)d_in[18]; const float* lk1 = (const float*)d_in[19];
  const float* lq2 = (const float*)d_in[20]; const float* lk2 = (const float*)d_in[21];

  char* p = (char*)d_ws;
  float* S_part = (float*)p;  p += (size_t)64 * 65536 * 4;
  float* skp = (float*)p;     p += 64 * 256 * 4;
  float* svp = (float*)p;     p += 64 * 256 * 4;
  float* Pc_part = (float*)p; p += (size_t)16 * 65536 * 4;
  float* S  = (float*)p;      p += 65536 * 4;
  float* Pc = (float*)p;      p += 65536 * 4;
  float* sk = (float*)p;      p += 1024;
  float* sv = (float*)p;      p += 1024;
  float* gc = (float*)p;      p += 1024;
  float* uc = (float*)p;      p += 1024;
  float* tc = (float*)p;      p += 1024;
  float* rv = (float*)p;      p += 1024;
  float* wv_ = (float*)p;     p += 2048 * 4;
  float* cc  = (float*)p;     p += 2048 * 4;
  float* Ac  = (float*)p;     p += 65536 * 4;
  float* Gc  = (float*)p;     p += (size_t)2048 * 256 * 4;
  float* M_part  = (float*)p; p += (size_t)4 * 65536 * 4;
  float* Hc_part = (float*)p; p += (size_t)4 * 288 * 256 * 4;
  unsigned short* Bbt = (unsigned short*)p; p += (size_t)528 * 256 * 2;
  float* wbar = (float*)p;    p += 1024;
  float* hcv  = (float*)p;    p += 1024;
  float* bcv  = (float*)p;    p += 1024;
  float* scal = (float*)p;    p += 256;

  const dim3 b256(256);
  k_lambda<<<dim3(1), b256, 0, stream>>>(lq1, lk1, lq2, lk2, bq1, bk1, bq2, bk2, layer, scal);
  k_s<<<dim3(2, 2, 64), b256, 0, stream>>>(k, v, S_part, skp, svp);
  k_pc<<<dim3(2, 2, 16), b256, 0, stream>>>(Wq1, Wk1, Wq2, Wk2, scal, Pc_part);
  k_sred<<<dim3(546), b256, 0, stream>>>(S_part, Pc_part, skp, svp, S, Pc, sk, sv,
                                         Wk1, Wk2, Wq1, Wq2, bq1, bq2, bk1, bk2, scal, gc, uc);
  k_ac<<<dim3(34), b256, 0, stream>>>(Pc, S, gc, sk, Ac, tc, rv, scal);
  k_wcc<<<dim3(16), b256, 0, stream>>>(Wv, sv, rv, bv, scal, wv_, cc);
  k_gc<<<dim3(4, 16), b256, 0, stream>>>(Ac, Wv, tc, uc, wv_, bv, Gc);
  k_post<<<dim3(417), b256, 0, stream>>>(Gc, cc, Wo, lng, lnb, scal, Bbt, M_part, Hc_part, scal);
  k_red2<<<dim3(4, 3), b256, 0, stream>>>(M_part, Hc_part, bo, Bbt, wbar, hcv, bcv);
  k_out<<<dim3(625), b256, 0, stream>>>(q, Bbt, hcv, wbar, bcv, scal, (float*)d_out);
}

// Round 5
// 181.914 us; speedup vs baseline: 1.9444x; 1.2562x over previous
//
#include <hip/hip_runtime.h>
#include <stdint.h>

typedef __bf16 bf16x8 __attribute__((ext_vector_type(8)));
typedef float f32x4 __attribute__((ext_vector_type(4)));
typedef float f32x2 __attribute__((ext_vector_type(2)));
typedef unsigned short u16x4 __attribute__((ext_vector_type(4)));
typedef unsigned short u16x8 __attribute__((ext_vector_type(8)));

#define NTOK 20000
#define HIW  256
#define HD   2048

static __device__ __forceinline__ unsigned short f2bf(float f) {
  union { float f; unsigned u; } c; c.f = f;
  unsigned u = c.u + (0x7fffu + ((c.u >> 16) & 1u));   // RNE
  return (unsigned short)(u >> 16);
}
static __device__ __forceinline__ float bf2f(unsigned short h) {
  union { unsigned u; float f; } c; c.u = ((unsigned)h) << 16;
  return c.f;
}

#define WRED(x) { x += __shfl_xor(x,32); x += __shfl_xor(x,16); x += __shfl_xor(x,8); \
                  x += __shfl_xor(x,4);  x += __shfl_xor(x,2);  x += __shfl_xor(x,1); }

// ============ k_front: [0,256) k_s | [256,384) k_pc (pair-split) | 384 lambda ============
// scal: 0=lam 1=-lam 2=1-li 3=li 4=dc 5=alpha_c 6=css 7=cbar
__global__ __launch_bounds__(256) void k_front(
    const float* __restrict__ kk, const float* __restrict__ vv,
    const float* __restrict__ Wq1, const float* __restrict__ Wk1,
    const float* __restrict__ Wq2, const float* __restrict__ Wk2,
    const float* __restrict__ lq1, const float* __restrict__ lk1,
    const float* __restrict__ lq2, const float* __restrict__ lk2,
    const float* __restrict__ bq1, const float* __restrict__ bk1,
    const float* __restrict__ bq2, const float* __restrict__ bk2,
    const int* __restrict__ layer,
    float* __restrict__ S_part, float* __restrict__ skp, float* __restrict__ svp,
    float* __restrict__ Pc_part, float* __restrict__ scal) {
  __shared__ unsigned short SH[4 * 128 * 72];
  unsigned short* Ahi = SH;
  unsigned short* Alo = SH + 128 * 72;
  unsigned short* Bhi = SH + 2 * 128 * 72;
  unsigned short* Blo = SH + 3 * 128 * 72;
  const int b = blockIdx.x;
  const int t = threadIdx.x, lane = t & 63, wave = t >> 6;
  const int wr = (wave >> 1) * 64, wc = (wave & 1) * 64;
  const int r15 = lane & 15;

  if (b < 256) {
    // ----- S_part[z] = k^T v over n-chunk z (hi/lo split, swizzled LDS) -----
    const int z = b & 63, by = (b >> 6) & 1, bx = (b >> 7) & 1;
    const int i0 = bx * 128, j0 = by * 128;
    const bool diag = (bx == by);
    const int n_lo = z * 313;
    const int cnt = (NTOK - n_lo < 313) ? (NTOK - n_lo) : 313;
    f32x4 acc[4][4];
    #pragma unroll
    for (int m = 0; m < 4; ++m)
      #pragma unroll
      for (int n = 0; n < 4; ++n) acc[m][n] = (f32x4){0.f, 0.f, 0.f, 0.f};
    f32x4 ksum = {0.f, 0.f, 0.f, 0.f}, vsum = {0.f, 0.f, 0.f, 0.f};
    const int r0 = t >> 5, c4 = (t & 31) * 4;
    const int wkey = t & 7;

    for (int kt = 0; kt < 5; ++kt) {
      __syncthreads();
      #pragma unroll
      for (int it = 0; it < 8; ++it) {
        const int nn = kt * 64 + it * 8 + r0;
        const bool valid = nn < cnt;
        const int gn = n_lo + nn;
        f32x4 a = {0.f, 0.f, 0.f, 0.f}, bb = {0.f, 0.f, 0.f, 0.f};
        if (valid) {
          a = *(const f32x4*)&kk[(size_t)gn * HIW + i0 + c4];
          bb = *(const f32x4*)&vv[(size_t)gn * HIW + j0 + c4];
        }
        ksum += a; vsum += bb;
        const int cb = ((it ^ wkey) << 3) + r0;
        #pragma unroll
        for (int u = 0; u < 4; ++u) {
          unsigned short h = f2bf(a[u]);
          Ahi[(c4 + u) * 72 + cb] = h;
          Alo[(c4 + u) * 72 + cb] = f2bf(a[u] - bf2f(h));
          h = f2bf(bb[u]);
          Bhi[(c4 + u) * 72 + cb] = h;
          Blo[(c4 + u) * 72 + cb] = f2bf(bb[u] - bf2f(h));
        }
      }
      __syncthreads();
      #pragma unroll
      for (int ks = 0; ks < 2; ++ks) {
        const int kb = ks * 4 + (lane >> 4);
        bf16x8 ah[4], al[4], bh[4], bl[4];
        #pragma unroll
        for (int m = 0; m < 4; ++m) {
          const int row = wr + m * 16 + r15;
          const int off = row * 72 + ((kb ^ ((row >> 2) & 7)) << 3);
          ah[m] = *(const bf16x8*)&Ahi[off];
          al[m] = *(const bf16x8*)&Alo[off];
        }
        #pragma unroll
        for (int n = 0; n < 4; ++n) {
          const int row = wc + n * 16 + r15;
          const int off = row * 72 + ((kb ^ ((row >> 2) & 7)) << 3);
          bh[n] = *(const bf16x8*)&Bhi[off];
          bl[n] = *(const bf16x8*)&Blo[off];
        }
        #pragma unroll
        for (int m = 0; m < 4; ++m)
          #pragma unroll
          for (int n = 0; n < 4; ++n) {
            acc[m][n] = __builtin_amdgcn_mfma_f32_16x16x32_bf16(ah[m], bh[n], acc[m][n], 0, 0, 0);
            acc[m][n] = __builtin_amdgcn_mfma_f32_16x16x32_bf16(ah[m], bl[n], acc[m][n], 0, 0, 0);
            acc[m][n] = __builtin_amdgcn_mfma_f32_16x16x32_bf16(al[m], bh[n], acc[m][n], 0, 0, 0);
          }
      }
    }
    const int rg = (lane >> 4) * 4;
    #pragma unroll
    for (int m = 0; m < 4; ++m)
      #pragma unroll
      for (int n = 0; n < 4; ++n)
        #pragma unroll
        for (int r = 0; r < 4; ++r)
          S_part[(size_t)z * 65536 + (i0 + wr + m * 16 + rg + r) * 256 + (j0 + wc + n * 16 + r15)] =
              acc[m][n][r];
    if (diag) {
      __syncthreads();
      float* red = (float*)SH;
      *(f32x4*)&red[r0 * 128 + c4] = ksum;
      *(f32x4*)&red[1024 + r0 * 128 + c4] = vsum;
      __syncthreads();
      const int col = t & 127, which = t >> 7;
      float s = 0.f;
      #pragma unroll
      for (int r = 0; r < 8; ++r) s += red[which * 1024 + r * 128 + col];
      if (which == 0) skp[z * 256 + i0 + col] = s;
      else            svp[z * 256 + j0 + col] = s;
    }
  } else if (b < 384) {
    // ----- Pc_part[pair*16+z] = Wa Wb^T K-slice (hi/lo, unscaled) -----
    const int idx = b - 256;
    const int pair = idx >> 6, rem = idx & 63;
    const int z = rem & 15, by = (rem >> 4) & 1, bx = (rem >> 5) & 1;
    const int i0 = bx * 128, j0 = by * 128;
    const float* Wa = pair ? Wq2 : Wq1;
    const float* Wb = pair ? Wk2 : Wk1;
    f32x4 acc[4][4];
    #pragma unroll
    for (int m = 0; m < 4; ++m)
      #pragma unroll
      for (int n = 0; n < 4; ++n) acc[m][n] = (f32x4){0.f, 0.f, 0.f, 0.f};
    const int srow = t >> 1, sh = (t & 1) * 32;
    const int kg = (lane >> 4) * 8;
    for (int kt = 0; kt < 2; ++kt) {
      const int kb = z * 128 + kt * 64 + sh;
      __syncthreads();
      #pragma unroll
      for (int c = 0; c < 8; ++c) {
        f32x4 a = *(const f32x4*)&Wa[(size_t)(i0 + srow) * HD + kb + c * 4];
        f32x4 bb = *(const f32x4*)&Wb[(size_t)(j0 + srow) * HD + kb + c * 4];
        #pragma unroll
        for (int u = 0; u < 4; ++u) {
          unsigned short h = f2bf(a[u]);
          Ahi[srow * 72 + sh + c * 4 + u] = h;
          Alo[srow * 72 + sh + c * 4 + u] = f2bf(a[u] - bf2f(h));
          h = f2bf(bb[u]);
          Bhi[srow * 72 + sh + c * 4 + u] = h;
          Blo[srow * 72 + sh + c * 4 + u] = f2bf(bb[u] - bf2f(h));
        }
      }
      __syncthreads();
      #pragma unroll
      for (int ks = 0; ks < 2; ++ks) {
        const int ko = ks * 32 + kg;
        bf16x8 ah[4], al[4], bh[4], bl[4];
        #pragma unroll
        for (int m = 0; m < 4; ++m) {
          ah[m] = *(const bf16x8*)&Ahi[(wr + m * 16 + r15) * 72 + ko];
          al[m] = *(const bf16x8*)&Alo[(wr + m * 16 + r15) * 72 + ko];
        }
        #pragma unroll
        for (int n = 0; n < 4; ++n) {
          bh[n] = *(const bf16x8*)&Bhi[(wc + n * 16 + r15) * 72 + ko];
          bl[n] = *(const bf16x8*)&Blo[(wc + n * 16 + r15) * 72 + ko];
        }
        #pragma unroll
        for (int m = 0; m < 4; ++m)
          #pragma unroll
          for (int n = 0; n < 4; ++n) {
            acc[m][n] = __builtin_amdgcn_mfma_f32_16x16x32_bf16(ah[m], bh[n], acc[m][n], 0, 0, 0);
            acc[m][n] = __builtin_amdgcn_mfma_f32_16x16x32_bf16(ah[m], bl[n], acc[m][n], 0, 0, 0);
            acc[m][n] = __builtin_amdgcn_mfma_f32_16x16x32_bf16(al[m], bh[n], acc[m][n], 0, 0, 0);
          }
      }
    }
    const int rg = (lane >> 4) * 4;
    #pragma unroll
    for (int m = 0; m < 4; ++m)
      #pragma unroll
      for (int n = 0; n < 4; ++n)
        #pragma unroll
        for (int r = 0; r < 4; ++r)
          Pc_part[(size_t)(pair * 16 + z) * 65536 +
                  (i0 + wr + m * 16 + rg + r) * 256 + (j0 + wc + n * 16 + r15)] = acc[m][n][r];
  } else {
    // ----- lambda scalars -----
    float p1 = lq1[t] * lk1[t], p2 = lq2[t] * lk2[t];
    float d1 = 0.f, d2 = 0.f;
    #pragma unroll
    for (int u = 0; u < 8; ++u) {
      d1 += bq1[t * 8 + u] * bk1[t * 8 + u];
      d2 += bq2[t * 8 + u] * bk2[t * 8 + u];
    }
    WRED(p1); WRED(p2); WRED(d1); WRED(d2);
    float* red = (float*)SH;
    int w = t >> 6;
    if ((t & 63) == 0) { red[w] = p1; red[4 + w] = p2; red[8 + w] = d1; red[12 + w] = d2; }
    __syncthreads();
    if (t == 0) {
      float s1 = red[0] + red[1] + red[2] + red[3];
      float s2 = red[4] + red[5] + red[6] + red[7];
      float dd1 = red[8] + red[9] + red[10] + red[11];
      float dd2 = red[12] + red[13] + red[14] + red[15];
      float li = 0.8f - 0.6f * expf(-0.3f * (float)layer[0]);
      float lam = expf(s1) - expf(s2) + li;
      scal[0] = lam; scal[1] = -lam; scal[2] = 1.0f - li; scal[3] = li;
      scal[4] = dd1 - lam * dd2;
    }
  }
}

// reductions + gc/uc matvecs
__global__ __launch_bounds__(256) void k_sred(
    const float* __restrict__ S_part, const float* __restrict__ Pc_part,
    const float* __restrict__ skp, const float* __restrict__ svp,
    float* __restrict__ S, float* __restrict__ Pc,
    float* __restrict__ sk, float* __restrict__ sv,
    const float* __restrict__ Wk1, const float* __restrict__ Wk2,
    const float* __restrict__ Wq1, const float* __restrict__ Wq2,
    const float* __restrict__ bq1, const float* __restrict__ bq2,
    const float* __restrict__ bk1, const float* __restrict__ bk2,
    const float* __restrict__ scal, float* __restrict__ gc, float* __restrict__ uc) {
  int b = blockIdx.x, t = threadIdx.x;
  if (b < 256) {
    int idx = b * 256 + t;
    float s = 0.f;
    for (int z = 0; z < 64; ++z) s += S_part[(size_t)z * 65536 + idx];
    S[idx] = s;
  } else if (b < 512) {
    int idx = (b - 256) * 256 + t;
    float s1 = 0.f, s2 = 0.f;
    #pragma unroll
    for (int z = 0; z < 16; ++z) {
      s1 += Pc_part[(size_t)z * 65536 + idx];
      s2 += Pc_part[(size_t)(16 + z) * 65536 + idx];
    }
    Pc[idx] = s1 - scal[0] * s2;
  } else if (b < 514) {
    const float* src = (b == 512) ? skp : svp;
    float s = 0.f;
    for (int z = 0; z < 64; ++z) s += src[z * 256 + t];
    if (b == 512) sk[t] = s; else sv[t] = s;
  } else {
    int bb = b - 514, lane = t & 63, w = t >> 6;
    bool dogc = bb < 16;
    const float* A1 = dogc ? Wk1 : Wq1;
    const float* A2 = dogc ? Wk2 : Wq2;
    const float* x1 = dogc ? bq1 : bk1;
    const float* x2 = dogc ? bq2 : bk2;
    float* outv = dogc ? gc : uc;
    float lam = scal[0];
    int rb = (bb & 15) * 16 + w * 4;
    for (int q2 = 0; q2 < 4; ++q2) {
      int row = rb + q2;
      float s1 = 0.f, s2 = 0.f;
      #pragma unroll
      for (int c = 0; c < 8; ++c) {
        int kk2 = c * 256 + lane * 4;
        f32x4 a1 = *(const f32x4*)&A1[(size_t)row * HD + kk2];
        f32x4 a2 = *(const f32x4*)&A2[(size_t)row * HD + kk2];
        f32x4 v1 = *(const f32x4*)&x1[kk2];
        f32x4 v2 = *(const f32x4*)&x2[kk2];
        #pragma unroll
        for (int u = 0; u < 4; ++u) { s1 += a1[u] * v1[u]; s2 += a2[u] * v2[u]; }
      }
      WRED(s1); WRED(s2);
      if (lane == 0) outv[row] = s1 - lam * s2;
    }
  }
}

// Ac = Pc @ S ; tc = Pc @ sk ; rv = S^T gc ; alpha_c = gc . sk
__global__ __launch_bounds__(256) void k_ac(
    const float* __restrict__ Pc, const float* __restrict__ S,
    const float* __restrict__ gc, const float* __restrict__ sk,
    float* __restrict__ Ac, float* __restrict__ tc, float* __restrict__ rv,
    float* __restrict__ scal) {
  int b = blockIdx.x, t = threadIdx.x;
  if (b < 32) {
    __shared__ float Pt[32][68];
    __shared__ float St[64][68];
    int i0 = (b >> 2) * 32, j0 = (b & 3) * 64;
    int ti = t >> 5, tj = t & 31;
    float acc[4][2] = {};
    for (int kt = 0; kt < 256; kt += 64) {
      __syncthreads();
      {
        int rr = t >> 3, c8 = (t & 7) * 8;
        *(f32x4*)&Pt[rr][c8] = *(const f32x4*)&Pc[(i0 + rr) * 256 + kt + c8];
        *(f32x4*)&Pt[rr][c8 + 4] = *(const f32x4*)&Pc[(i0 + rr) * 256 + kt + c8 + 4];
      }
      {
        int rr = t >> 2, c16 = (t & 3) * 16;
        #pragma unroll
        for (int c = 0; c < 4; ++c)
          *(f32x4*)&St[rr][c16 + c * 4] = *(const f32x4*)&S[(kt + rr) * 256 + j0 + c16 + c * 4];
      }
      __syncthreads();
      #pragma unroll 8
      for (int k2 = 0; k2 < 64; ++k2) {
        float a[4];
        #pragma unroll
        for (int u = 0; u < 4; ++u) a[u] = Pt[ti * 4 + u][k2];
        f32x2 b2 = *(const f32x2*)&St[k2][tj * 2];
        #pragma unroll
        for (int u = 0; u < 4; ++u) { acc[u][0] += a[u] * b2[0]; acc[u][1] += a[u] * b2[1]; }
      }
    }
    #pragma unroll
    for (int u = 0; u < 4; ++u) {
      Ac[(i0 + ti * 4 + u) * 256 + j0 + tj * 2] = acc[u][0];
      Ac[(i0 + ti * 4 + u) * 256 + j0 + tj * 2 + 1] = acc[u][1];
    }
  } else if (b == 32) {
    int lane = t & 63, w = t >> 6;
    f32x4 sk4 = *(const f32x4*)&sk[lane * 4];
    for (int ii = 0; ii < 64; ++ii) {
      int i = w * 64 + ii;
      f32x4 p4 = *(const f32x4*)&Pc[i * 256 + lane * 4];
      float s = p4[0] * sk4[0] + p4[1] * sk4[1] + p4[2] * sk4[2] + p4[3] * sk4[3];
      WRED(s);
      if (lane == 0) tc[i] = s;
    }
  } else {
    float s0 = 0.f, s1 = 0.f, s2 = 0.f, s3 = 0.f;
    #pragma unroll 4
    for (int i = 0; i < 256; i += 4) {
      s0 += gc[i] * S[i * 256 + t];
      s1 += gc[i + 1] * S[(i + 1) * 256 + t];
      s2 += gc[i + 2] * S[(i + 2) * 256 + t];
      s3 += gc[i + 3] * S[(i + 3) * 256 + t];
    }
    rv[t] = (s0 + s1) + (s2 + s3);
    if (t < 64) {
      f32x4 g4 = *(const f32x4*)&gc[t * 4];
      f32x4 sk4 = *(const f32x4*)&sk[t * 4];
      float a = g4[0] * sk4[0] + g4[1] * sk4[1] + g4[2] * sk4[2] + g4[3] * sk4[3];
      WRED(a);
      if (t == 0) scal[5] = a;
    }
  }
}

// partial matvecs: part[iseg*2+0][j] = sum Wv[i,j] sv[i] ; +1 -> rv   (8 isegs x 16 jblks)
__global__ __launch_bounds__(256) void k_wcc_part(
    const float* __restrict__ Wv, const float* __restrict__ sv,
    const float* __restrict__ rv, float* __restrict__ part) {
  __shared__ float red[2][2][128];
  int t = threadIdx.x;
  int jblk = blockIdx.x & 15, iseg = blockIdx.x >> 4;
  int j = jblk * 128 + (t & 127);
  int half = t >> 7;
  int ib = iseg * 32 + half * 16;
  float sw = 0.f, sc = 0.f;
  #pragma unroll
  for (int u = 0; u < 16; ++u) {
    float w = Wv[(size_t)(ib + u) * HD + j];
    sw += w * sv[ib + u];
    sc += w * rv[ib + u];
  }
  red[half][0][t & 127] = sw;
  red[half][1][t & 127] = sc;
  __syncthreads();
  if (half == 0) {
    sw += red[1][0][t & 127];
    sc += red[1][1][t & 127];
    part[(iseg * 2) * 2048 + j] = sw;
    part[(iseg * 2 + 1) * 2048 + j] = sc;
  }
}

// Gc = Ac @ Wv + tc bv^T + uc (w + N bv)^T ; also materializes cc
__global__ __launch_bounds__(256) void k_gc(
    const float* __restrict__ Ac, const float* __restrict__ Wv,
    const float* __restrict__ tc, const float* __restrict__ uc,
    const float* __restrict__ part, const float* __restrict__ bv,
    const float* __restrict__ scal, float* __restrict__ Gc, float* __restrict__ cc) {
  __shared__ float At[64][68];
  __shared__ float Bt[64][132];
  int t = threadIdx.x;
  int i0 = blockIdx.x * 64, j0 = blockIdx.y * 128;
  int ti = t >> 5, tj = t & 31;
  float acc[8][4] = {};
  for (int kt = 0; kt < 256; kt += 64) {
    __syncthreads();
    {
      int rr = t >> 2, c16 = (t & 3) * 16;
      #pragma unroll
      for (int c = 0; c < 4; ++c)
        *(f32x4*)&At[rr][c16 + c * 4] = *(const f32x4*)&Ac[(i0 + rr) * 256 + kt + c16 + c * 4];
    }
    {
      int rr = t >> 2, c32 = (t & 3) * 32;
      #pragma unroll
      for (int c = 0; c < 8; ++c)
        *(f32x4*)&Bt[rr][c32 + c * 4] = *(const f32x4*)&Wv[(size_t)(kt + rr) * HD + j0 + c32 + c * 4];
    }
    __syncthreads();
    #pragma unroll 8
    for (int k2 = 0; k2 < 64; ++k2) {
      float a[8];
      #pragma unroll
      for (int u = 0; u < 8; ++u) a[u] = At[ti * 8 + u][k2];
      f32x4 b = *(const f32x4*)&Bt[k2][tj * 4];
      #pragma unroll
      for (int u = 0; u < 8; ++u)
        #pragma unroll
        for (int v = 0; v < 4; ++v) acc[u][v] += a[u] * b[v];
    }
  }
  int j = j0 + tj * 4;
  f32x4 sw4 = {0.f, 0.f, 0.f, 0.f}, sc4 = {0.f, 0.f, 0.f, 0.f};
  #pragma unroll
  for (int p = 0; p < 8; ++p) {
    sw4 += *(const f32x4*)&part[(p * 2) * 2048 + j];
    sc4 += *(const f32x4*)&part[(p * 2 + 1) * 2048 + j];
  }
  f32x4 bv4 = *(const f32x4*)&bv[j];
  f32x4 wnb;
  #pragma unroll
  for (int v = 0; v < 4; ++v) wnb[v] = sw4[v] + 20000.0f * bv4[v];
  if (blockIdx.x == 0 && ti == 0) {
    float ac = scal[5], dc = scal[4];
    f32x4 ccv;
    #pragma unroll
    for (int v = 0; v < 4; ++v) ccv[v] = sc4[v] + ac * bv4[v] + dc * wnb[v];
    *(f32x4*)&cc[j] = ccv;
  }
  #pragma unroll
  for (int u = 0; u < 8; ++u) {
    int i = i0 + ti * 8 + u;
    float tci = tc[i], uci = uc[i];
    f32x4 o;
    #pragma unroll
    for (int v = 0; v < 4; ++v)
      o[v] = acc[u][v] + tci * bv4[v] + uci * wnb[v];
    *(f32x4*)&Gc[(size_t)i * HD + j] = o;
  }
}

// merged: [0,17) scal2 | [17,273) M = Gc Gc^T partials | [273,417) Hc partials
__global__ __launch_bounds__(256) void k_post(
    const float* __restrict__ Gc, const float* __restrict__ cc,
    const float* __restrict__ Wo, const float* __restrict__ g,
    const float* __restrict__ lnb, const float* __restrict__ scal_c,
    unsigned short* __restrict__ Bbt, float* __restrict__ M_part,
    float* __restrict__ Hc_part, float* __restrict__ scal) {
  __shared__ float SMEM[6528];
  int b = blockIdx.x, t = threadIdx.x;
  if (b < 17) {
    int lane = t & 63, w = t >> 6;
    if (b < 16) {
      int rb = b * 16 + w * 4;
      for (int q2 = 0; q2 < 4; ++q2) {
        int row = rb + q2;
        float s1 = 0.f, s2 = 0.f;
        #pragma unroll
        for (int c = 0; c < 8; ++c) {
          int kk2 = c * 256 + lane * 4;
          f32x4 g4 = *(const f32x4*)&Gc[(size_t)row * HD + kk2];
          f32x4 c4v = *(const f32x4*)&cc[kk2];
          #pragma unroll
          for (int u = 0; u < 4; ++u) { s1 += g4[u]; s2 += g4[u] * c4v[u]; }
        }
        WRED(s1); WRED(s2);
        if (lane == 0) {
          Bbt[512 * 256 + row] = f2bf(s1 * (1.0f / 2048.0f));
          Bbt[513 * 256 + row] = f2bf(s2);
        }
      }
    } else {
      float s1 = 0.f, s2 = 0.f;
      #pragma unroll
      for (int c = 0; c < 2; ++c) {
        f32x4 v = *(const f32x4*)&cc[t * 8 + c * 4];
        #pragma unroll
        for (int u = 0; u < 4; ++u) { s1 += v[u]; s2 += v[u] * v[u]; }
      }
      WRED(s1); WRED(s2);
      if (lane == 0) { SMEM[w] = s1; SMEM[4 + w] = s2; }
      __syncthreads();
      if (t == 0) {
        scal[6] = SMEM[4] + SMEM[5] + SMEM[6] + SMEM[7];
        scal[7] = (SMEM[0] + SMEM[1] + SMEM[2] + SMEM[3]) * (1.0f / 2048.0f);
      }
      for (int idx = t; idx < 14 * 256; idx += 256) Bbt[514 * 256 + idx] = 0;
    }
  } else if (b < 273) {
    float (*Gi)[68] = (float(*)[68])SMEM;
    float (*Gj)[68] = (float(*)[68])(SMEM + 32 * 68);
    int idx = b - 17;
    int bx = idx & 7, by = (idx >> 3) & 7, z = idx >> 6;
    int i0 = bx * 32, j0 = by * 32;
    int ti = t >> 4, tj = t & 15;
    float acc[2][2] = {};
    for (int kt = 0; kt < 512; kt += 64) {
      int kb = z * 512 + kt;
      __syncthreads();
      {
        int rr = t >> 3, c8 = (t & 7) * 8;
        *(f32x4*)&Gi[rr][c8] = *(const f32x4*)&Gc[(size_t)(i0 + rr) * HD + kb + c8];
        *(f32x4*)&Gi[rr][c8 + 4] = *(const f32x4*)&Gc[(size_t)(i0 + rr) * HD + kb + c8 + 4];
        *(f32x4*)&Gj[rr][c8] = *(const f32x4*)&Gc[(size_t)(j0 + rr) * HD + kb + c8];
        *(f32x4*)&Gj[rr][c8 + 4] = *(const f32x4*)&Gc[(size_t)(j0 + rr) * HD + kb + c8 + 4];
      }
      __syncthreads();
      #pragma unroll 8
      for (int k2 = 0; k2 < 64; ++k2) {
        float a0 = Gi[ti * 2][k2], a1 = Gi[ti * 2 + 1][k2];
        float b0 = Gj[tj * 2][k2], b1 = Gj[tj * 2 + 1][k2];
        acc[0][0] += a0 * b0; acc[0][1] += a0 * b1;
        acc[1][0] += a1 * b0; acc[1][1] += a1 * b1;
      }
    }
    #pragma unroll
    for (int u = 0; u < 2; ++u)
      #pragma unroll
      for (int v = 0; v < 2; ++v)
        M_part[(size_t)z * 65536 + (i0 + ti * 2 + u) * 256 + j0 + tj * 2 + v] = acc[u][v];
  } else {
    float (*At)[68] = (float(*)[68])SMEM;
    float (*Bt)[68] = (float(*)[68])(SMEM + 32 * 68);
    int idx = b - 273;
    int bx = idx % 9, rem = idx / 9, by = rem & 3, z = rem >> 2;
    int i0 = bx * 32, j0 = by * 64;
    float s2 = scal_c[2];
    int ti = t >> 5, tj = t & 31;
    float acc[4][2] = {};
    for (int kt = 0; kt < 512; kt += 64) {
      int kb = z * 512 + kt;
      __syncthreads();
      {
        int rr = t >> 3, c8 = (t & 7) * 8, gi = i0 + rr;
        #pragma unroll
        for (int h = 0; h < 8; h += 4) {
          f32x4 g4 = *(const f32x4*)&g[kb + c8 + h];
          f32x4 a;
          if (gi < 256) {
            f32x4 gg = *(const f32x4*)&Gc[(size_t)gi * HD + kb + c8 + h];
            #pragma unroll
            for (int u = 0; u < 4; ++u) a[u] = gg[u] * g4[u];
          } else if (gi == 256) {
            a = g4;
          } else if (gi == 257) {
            f32x4 c4v = *(const f32x4*)&cc[kb + c8 + h];
            #pragma unroll
            for (int u = 0; u < 4; ++u) a[u] = c4v[u] * g4[u];
          } else if (gi == 258) {
            a = *(const f32x4*)&lnb[kb + c8 + h];
          } else {
            a = (f32x4){0.f, 0.f, 0.f, 0.f};
          }
          *(f32x4*)&At[rr][c8 + h] = a;
        }
      }
      {
        int rr = t >> 2, c16 = (t & 3) * 16;
        #pragma unroll
        for (int c = 0; c < 4; ++c) {
          f32x4 bb = *(const f32x4*)&Wo[(size_t)(kb + rr) * 256 + j0 + c16 + c * 4];
          #pragma unroll
          for (int u = 0; u < 4; ++u) bb[u] *= s2;
          *(f32x4*)&Bt[rr][c16 + c * 4] = bb;
        }
      }
      __syncthreads();
      #pragma unroll 8
      for (int k2 = 0; k2 < 64; ++k2) {
        float a[4];
        #pragma unroll
        for (int u = 0; u < 4; ++u) a[u] = At[ti * 4 + u][k2];
        f32x2 b2 = *(const f32x2*)&Bt[k2][tj * 2];
        #pragma unroll
        for (int u = 0; u < 4; ++u) { acc[u][0] += a[u] * b2[0]; acc[u][1] += a[u] * b2[1]; }
      }
    }
    #pragma unroll
    for (int u = 0; u < 4; ++u) {
      Hc_part[(size_t)z * 73728 + (i0 + ti * 4 + u) * 256 + j0 + tj * 2] = acc[u][0];
      Hc_part[(size_t)z * 73728 + (i0 + ti * 4 + u) * 256 + j0 + tj * 2 + 1] = acc[u][1];
    }
  }
}

// reduce M/Hc partials -> Bbt (transposed, bf16); vectors wbar/hc/bc
__global__ __launch_bounds__(256) void k_red2(
    const float* __restrict__ M_part, const float* __restrict__ Hc_part,
    const float* __restrict__ bo, unsigned short* __restrict__ Bbt,
    float* __restrict__ wbar, float* __restrict__ hcv, float* __restrict__ bcv) {
  int bi = blockIdx.x, z2 = blockIdx.y, t = threadIdx.x;
  if (z2 == 2) {
    if (bi != 0) return;
    float s0 = 0.f, s1 = 0.f, s2 = 0.f;
    #pragma unroll
    for (int z = 0; z < 4; ++z) {
      s0 += Hc_part[(size_t)z * 73728 + 256 * 256 + t];
      s1 += Hc_part[(size_t)z * 73728 + 257 * 256 + t];
      s2 += Hc_part[(size_t)z * 73728 + 258 * 256 + t];
    }
    wbar[t] = s0; hcv[t] = s1; bcv[t] = s2 + bo[t];
    return;
  }
  __shared__ unsigned short T[64][256];
  const float* src = z2 ? Hc_part : M_part;
  const size_t sp = z2 ? 73728 : 65536;
  const int base = z2 ? 256 : 0;
  for (int ii = 0; ii < 64; ++ii) {
    int i = bi * 64 + ii;
    float s = 0.f;
    #pragma unroll
    for (int z = 0; z < 4; ++z) s += src[z * sp + i * 256 + t];
    T[ii][t] = f2bf(s);
  }
  __syncthreads();
  #pragma unroll
  for (int c = 0; c < 64; c += 8) {
    u16x8 o;
    #pragma unroll
    for (int u = 0; u < 8; ++u) o[u] = T[c + u][t];
    *(u16x8*)&Bbt[(size_t)(base + t) * 256 + bi * 64 + c] = o;
  }
}

// fused final: y|z|mu|m2 = q @ Bbt^T, then LN-stats + output epilogue
__global__ __launch_bounds__(256) void k_out(
    const float* __restrict__ q, const unsigned short* __restrict__ Bbt,
    const float* __restrict__ hcv, const float* __restrict__ wbar,
    const float* __restrict__ bcv, const float* __restrict__ scal,
    float* __restrict__ out) {
  __shared__ unsigned short As[32 * 264];
  __shared__ float sqp[2][32];
  __shared__ float muL[32], m2L[32];
  const int t = threadIdx.x, lane = t & 63, wave = t >> 6;
  const int row0 = blockIdx.x * 32;
  const int r15 = lane & 15, kg = lane >> 4;
  {
    int r = t >> 3;
    #pragma unroll
    for (int ci = 0; ci < 8; ++ci) {
      int col = ci * 32 + (t & 7) * 4;
      f32x4 v = *(const f32x4*)&q[(size_t)(row0 + r) * HIW + col];
      u16x4 o;
      #pragma unroll
      for (int u = 0; u < 4; ++u) o[u] = f2bf(v[u]);
      *(u16x4*)&As[r * 264 + col] = o;
    }
  }
  __syncthreads();
  const int wc = wave * 128;
  f32x4 acc[2][9];
  #pragma unroll
  for (int m = 0; m < 2; ++m)
    #pragma unroll
    for (int n = 0; n < 9; ++n) acc[m][n] = (f32x4){0.f, 0.f, 0.f, 0.f};
  #pragma unroll
  for (int ko = 0; ko < 8; ++ko) {
    bf16x8 af0 = *(const bf16x8*)&As[r15 * 264 + ko * 32 + kg * 8];
    bf16x8 af1 = *(const bf16x8*)&As[(16 + r15) * 264 + ko * 32 + kg * 8];
    #pragma unroll
    for (int ni = 0; ni < 9; ++ni) {
      if (ni == 8 && wave != 3) continue;
      int colb = wc + ni * 16 + r15;
      bf16x8 bfr = *(const bf16x8*)&Bbt[(size_t)colb * 256 + ko * 32 + kg * 8];
      acc[0][ni] = __builtin_amdgcn_mfma_f32_16x16x32_bf16(af0, bfr, acc[0][ni], 0, 0, 0);
      acc[1][ni] = __builtin_amdgcn_mfma_f32_16x16x32_bf16(af1, bfr, acc[1][ni], 0, 0, 0);
    }
  }
  if (wave < 2) {
    #pragma unroll
    for (int m = 0; m < 2; ++m)
      #pragma unroll
      for (int r = 0; r < 4; ++r) {
        int rowl = m * 16 + kg * 4 + r;
        float p = 0.f;
        #pragma unroll
        for (int ni = 0; ni < 8; ++ni) {
          int col = wc + ni * 16 + r15;
          p += acc[m][ni][r] * bf2f(As[rowl * 264 + col]);
        }
        p += __shfl_xor(p, 1); p += __shfl_xor(p, 2);
        p += __shfl_xor(p, 4); p += __shfl_xor(p, 8);
        if (r15 == 0) sqp[wave][rowl] = p;
      }
  }
  if (wave == 3) {
    #pragma unroll
    for (int m = 0; m < 2; ++m)
      #pragma unroll
      for (int r = 0; r < 4; ++r) {
        int rowl = m * 16 + kg * 4 + r;
        if (r15 == 0) muL[rowl] = acc[m][8][r];
        if (r15 == 1) m2L[rowl] = acc[m][8][r];
      }
  }
  __syncthreads();
  if (wave >= 2) {
    const float css = scal[6], cbar = scal[7];
    #pragma unroll
    for (int m = 0; m < 2; ++m)
      #pragma unroll
      for (int r = 0; r < 4; ++r) {
        int rowl = m * 16 + kg * 4 + r;
        float mu = muL[rowl] + cbar;
        float ss = sqp[0][rowl] + sqp[1][rowl] + 2.0f * m2L[rowl] + css;
        float var = ss * (1.0f / 2048.0f) - mu * mu;
        float rstd = rsqrtf(var + 1e-5f);
        int grow = row0 + rowl;
        #pragma unroll
        for (int ni = 0; ni < 8; ++ni) {
          int oc = (wc - 256) + ni * 16 + r15;
          float zv = acc[m][ni][r] + hcv[oc];
          out[(size_t)grow * HIW + oc] = rstd * (zv - mu * wbar[oc]) + bcv[oc];
        }
      }
  }
}

extern "C" void kernel_launch(void* const* d_in, const int* in_sizes, int n_in,
                              void* d_out, int out_size, void* d_ws, size_t ws_size,
                              hipStream_t stream) {
  const float* q   = (const float*)d_in[0];
  const float* k   = (const float*)d_in[1];
  const float* v   = (const float*)d_in[2];
  const int* layer = (const int*)d_in[3];
  const float* Wq1 = (const float*)d_in[4];  const float* bq1 = (const float*)d_in[5];
  const float* Wk1 = (const float*)d_in[6];  const float* bk1 = (const float*)d_in[7];
  const float* Wq2 = (const float*)d_in[8];  const float* bq2 = (const float*)d_in[9];
  const float* Wk2 = (const float*)d_in[10]; const float* bk2 = (const float*)d_in[11];
  const float* Wv  = (const float*)d_in[12]; const float* bv  = (const float*)d_in[13];
  const float* lng = (const float*)d_in[14]; const float* lnb = (const float*)d_in[15];
  const float* Wo  = (const float*)d_in[16]; const float* bo  = (const float*)d_in[17];
  const float* lq1 = (const float*)d_in[18]; const float* lk1 = (const float*)d_in[19];
  const float* lq2 = (const float*)d_in[20]; const float* lk2 = (const float*)d_in[21];

  char* p = (char*)d_ws;
  float* S_part = (float*)p;  p += (size_t)64 * 65536 * 4;
  float* skp = (float*)p;     p += 64 * 256 * 4;
  float* svp = (float*)p;     p += 64 * 256 * 4;
  float* Pc_part = (float*)p; p += (size_t)32 * 65536 * 4;
  float* S  = (float*)p;      p += 65536 * 4;
  float* Pc = (float*)p;      p += 65536 * 4;
  float* sk = (float*)p;      p += 1024;
  float* sv = (float*)p;      p += 1024;
  float* gc = (float*)p;      p += 1024;
  float* uc = (float*)p;      p += 1024;
  float* tc = (float*)p;      p += 1024;
  float* rv = (float*)p;      p += 1024;
  float* wcc_part = (float*)p; p += (size_t)16 * 2048 * 4;
  float* cc  = (float*)p;     p += 2048 * 4;
  float* Ac  = (float*)p;     p += 65536 * 4;
  float* Gc  = (float*)p;     p += (size_t)2048 * 256 * 4;
  float* M_part  = (float*)p; p += (size_t)4 * 65536 * 4;
  float* Hc_part = (float*)p; p += (size_t)4 * 288 * 256 * 4;
  unsigned short* Bbt = (unsigned short*)p; p += (size_t)528 * 256 * 2;
  float* wbar = (float*)p;    p += 1024;
  float* hcv  = (float*)p;    p += 1024;
  float* bcv  = (float*)p;    p += 1024;
  float* scal = (float*)p;    p += 256;

  const dim3 b256(256);
  k_front<<<dim3(385), b256, 0, stream>>>(k, v, Wq1, Wk1, Wq2, Wk2,
      lq1, lk1, lq2, lk2, bq1, bk1, bq2, bk2, layer, S_part, skp, svp, Pc_part, scal);
  k_sred<<<dim3(546), b256, 0, stream>>>(S_part, Pc_part, skp, svp, S, Pc, sk, sv,
                                         Wk1, Wk2, Wq1, Wq2, bq1, bq2, bk1, bk2, scal, gc, uc);
  k_ac<<<dim3(34), b256, 0, stream>>>(Pc, S, gc, sk, Ac, tc, rv, scal);
  k_wcc_part<<<dim3(128), b256, 0, stream>>>(Wv, sv, rv, wcc_part);
  k_gc<<<dim3(4, 16), b256, 0, stream>>>(Ac, Wv, tc, uc, wcc_part, bv, scal, Gc, cc);
  k_post<<<dim3(417), b256, 0, stream>>>(Gc, cc, Wo, lng, lnb, scal, Bbt, M_part, Hc_part, scal);
  k_red2<<<dim3(4, 3), b256, 0, stream>>>(M_part, Hc_part, bo, Bbt, wbar, hcv, bcv);
  k_out<<<dim3(625), b256, 0, stream>>>(q, Bbt, hcv, wbar, bcv, scal, (float*)d_out);
}